// Round 10
// baseline (319.955 us; speedup 1.0000x reference)
//
#include <hip/hip_runtime.h>
#include <hip/hip_bf16.h>
#include <math.h>

// ---------------------------------------------------------------------------
// GCNEncoderWithGate R10:
//  - spmm XCD-sliced: combo = blockIdx&7 -> (feature-slice s in [0,4) x row-half).
//    With round-robin blockIdx->XCD, each XCD's gather working set is a 6.4MB
//    feature stripe (vs 25.6MB) -> per-XCD L2 compulsory traffic 4x lower.
//    64B/edge requests (32 feats), no line split. Correctness is mapping-agnostic.
//  - rest identical to R9 (racefree fg, unscaled G1 + dinv[src] in spmm1).
// ---------------------------------------------------------------------------

#define BUCKET_SHIFT 8
#define BUCKET_W 256
#define CAP 4864
#define NB_MAX 512
#define OSTRIDE 136

typedef __attribute__((ext_vector_type(8))) short bf16x8;
typedef __attribute__((ext_vector_type(4))) float f32x4;

__device__ __forceinline__ unsigned short f2bf(float x) {
    unsigned int u = __float_as_uint(x);
    unsigned int r = (u + 0x7FFFu + ((u >> 16) & 1u)) >> 16;   // RNE
    return (unsigned short)r;
}
__device__ __forceinline__ float blo(unsigned int u) { return __uint_as_float(u << 16); }
__device__ __forceinline__ float bhi(unsigned int u) { return __uint_as_float(u & 0xFFFF0000u); }

__device__ __forceinline__ void cvt_hilo8(const float* v, bf16x8& hi, bf16x8& lo) {
#pragma unroll
    for (int j = 0; j < 8; j++) {
        unsigned short h = f2bf(v[j]);
        float hf = __uint_as_float((unsigned int)h << 16);
        hi[j] = (short)h;
        lo[j] = (short)f2bf(v[j] - hf);
    }
}

__device__ __forceinline__ f32x4 MF(bf16x8 a, bf16x8 b, f32x4 c) {
    return __builtin_amdgcn_mfma_f32_16x16x32_bf16(a, b, c, 0, 0, 0);
}

// ---------------------- prep weights + cursor init (1 dispatch) -------------
__global__ __launch_bounds__(512)
void prepinit_kernel(const float* __restrict__ W0, const float* __restrict__ W1,
                     const float* __restrict__ W2, uint4* __restrict__ img,
                     int* __restrict__ bcursor, int NB) {
    int b = blockIdx.x, t = threadIdx.x;
    if (b < 12) {
        int idx = b * 512 + t;            // 0..6143 = 3*2048
        int c = idx & 127, kb = (idx >> 7) & 15, w = idx >> 11;
        const float* W = (w == 0) ? W0 : (w == 1) ? W1 : W2;
        bf16x8 hb;
#pragma unroll
        for (int j = 0; j < 8; j++) hb[j] = (short)f2bf(W[(size_t)(kb * 8 + j) * 128 + c]);
        img[w * 2048 + c * 16 + (kb ^ (c & 15))] = *(uint4*)&hb;
    } else {
        if (t < NB) bcursor[t] = 0;
    }
}

// ---------------------- partition ∪ gate (1 dispatch) -----------------------
__device__ __forceinline__ void partition_body(char* smem, int b, int t,
                                               const int* __restrict__ src,
                                               const int* __restrict__ dst,
                                               int* __restrict__ bucketCursor,
                                               unsigned int* __restrict__ part,
                                               int E, int NB, int chunk) {
    int* hist  = (int*)smem;
    int* basec = hist + NB_MAX;
    int e0 = b * chunk;
    int e1 = min(E, e0 + chunk);

    for (int i = t; i < NB; i += 512) hist[i] = 0;
    __syncthreads();
    for (int e = e0 + t; e < e1; e += 512) {
        int bb = dst[e] >> BUCKET_SHIFT;
        atomicAdd(&hist[bb], 1);
    }
    __syncthreads();
    for (int i = t; i < NB; i += 512) {
        int c = hist[i];
        basec[i] = c ? atomicAdd(&bucketCursor[i], c) : 0;
    }
    __syncthreads();
    for (int i = t; i < NB; i += 512) hist[i] = 0;
    __syncthreads();
    for (int e = e0 + t; e < e1; e += 512) {
        int d = dst[e], s = src[e];
        int bb = d >> BUCKET_SHIFT;
        int r = atomicAdd(&hist[bb], 1);
        int pos = basec[bb] + r;
        if (pos < CAP)
            part[(size_t)bb * CAP + pos] = ((unsigned int)(d & (BUCKET_W - 1)) << 17) | (unsigned int)s;
    }
}

__device__ __forceinline__ void gate_body(char* smem, int gb, int t,
                                          const float* __restrict__ x,
                                          const uint4* __restrict__ gimg,
                                          const float* __restrict__ gate_b,
                                          unsigned short* __restrict__ hpack, int n) {
    uint4* Wl = (uint4*)smem;
    unsigned short* OutS = (unsigned short*)(smem + 32768);
    int lane = t & 63, wv = t >> 6;
    int blockRow = gb * 128;

    for (int idx = t; idx < 2048; idx += 512) Wl[idx] = gimg[idx];

    bf16x8 Ahi[4], Alo[4];
    {
        int arow = blockRow + wv * 16 + (lane & 15);
        const float* ap = x + (size_t)min(arow, n - 1) * 128 + (lane >> 4) * 8;
#pragma unroll
        for (int s = 0; s < 4; s++) {
            float v[8];
            *(float4*)&v[0] = *(const float4*)&ap[s * 32];
            *(float4*)&v[4] = *(const float4*)&ap[s * 32 + 4];
            cvt_hilo8(v, Ahi[s], Alo[s]);
        }
    }
    __syncthreads();

    f32x4 acc[8];
#pragma unroll
    for (int nt = 0; nt < 8; nt++) acc[nt] = (f32x4)(0.f);
#pragma unroll
    for (int s = 0; s < 4; s++) {
        int kb = s * 4 + (lane >> 4);
#pragma unroll
        for (int nt = 0; nt < 8; nt++) {
            int c = nt * 16 + (lane & 15);
            bf16x8 bh = *(bf16x8*)&Wl[c * 16 + (kb ^ (lane & 15))];
            acc[nt] = MF(Ahi[s], bh, acc[nt]);
            acc[nt] = MF(Alo[s], bh, acc[nt]);
        }
    }

    int rl0 = wv * 16 + (lane >> 4) * 4;
#pragma unroll
    for (int nt = 0; nt < 8; nt++) {
        int c = nt * 16 + (lane & 15);
        float gb2 = gate_b[c];
#pragma unroll
        for (int r = 0; r < 4; r++) {
            int grow = min(blockRow + rl0 + r, n - 1);
            float xv = x[(size_t)grow * 128 + c];
            float hv = xv / (1.f + __expf(-(acc[nt][r] + gb2)));
            OutS[(rl0 + r) * OSTRIDE + c] = f2bf(hv);
        }
    }
    __syncthreads();
    {
        int row = t >> 2;
        int c0 = (t & 3) * 32;
        int grow = blockRow + row;
        if (grow < n) {
#pragma unroll
            for (int j = 0; j < 4; j++) {
                uint4 v = *(uint4*)&OutS[row * OSTRIDE + c0 + j * 8];
                *(uint4*)&hpack[(size_t)grow * 128 + c0 + j * 8] = v;
            }
        }
    }
}

__global__ __launch_bounds__(512)
void pg_kernel(const int* __restrict__ src, const int* __restrict__ dst,
               int* __restrict__ bucketCursor, unsigned int* __restrict__ part,
               int E, int NB, int chunk,
               const float* __restrict__ x, const uint4* __restrict__ gimg,
               const float* __restrict__ gate_b, unsigned short* __restrict__ hpack, int n) {
    __shared__ __align__(16) char smem[67584];
    int b = blockIdx.x, t = threadIdx.x;
    if (b < 256) partition_body(smem, b, t, src, dst, bucketCursor, part, E, NB, chunk);
    else         gate_body(smem, b - 256, t, x, gimg, gate_b, hpack, n);
}

// ------------------------------ bucket scan --------------------------------
__global__ __launch_bounds__(512)
void bucket_scan_kernel(const int* __restrict__ bucketCursor,
                        int* __restrict__ bucketBase, int NB) {
    __shared__ int sm[NB_MAX];
    int t = threadIdx.x;
    int v = (t < NB) ? min(bucketCursor[t], CAP) : 0;
    sm[t] = v;
    __syncthreads();
    for (int off = 1; off < NB_MAX; off <<= 1) {
        int a = (t >= off) ? sm[t - off] : 0;
        __syncthreads();
        sm[t] += a;
        __syncthreads();
    }
    if (t < NB) bucketBase[t + 1] = sm[t];
    if (t == 0) bucketBase[0] = 0;
}

// ---------------------- bucket_fill ∪ gemm1 (1 dispatch) --------------------
__device__ __forceinline__ void fill_body(char* smem, int b, int t,
                                          const unsigned int* __restrict__ part,
                                          const int* __restrict__ bucketBase,
                                          int* __restrict__ rowptr, float* __restrict__ dinv,
                                          int* __restrict__ col, int N, int NB) {
    unsigned int* eLDS = (unsigned int*)smem;
    int* deg  = (int*)(smem + CAP * 4);
    int* cur  = deg + BUCKET_W;
    int* wsum = cur + BUCKET_W;   // 8 ints

    int base = bucketBase[b];
    int cnt = bucketBase[b + 1] - base;

    for (int i = t; i < cnt; i += 512) eLDS[i] = part[(size_t)b * CAP + i];
    if (t < 256) deg[t] = 0;
    __syncthreads();
    for (int i = t; i < cnt; i += 512) atomicAdd(&deg[eLDS[i] >> 17], 1);
    __syncthreads();

    int v = (t < 256) ? deg[t] : 0;
    int incl = v;
    int lane = t & 63, w = t >> 6;
    for (int off = 1; off < 64; off <<= 1) {
        int u = __shfl_up(incl, off, 64);
        if (lane >= off) incl += u;
    }
    if (lane == 63) wsum[w] = incl;
    __syncthreads();
    int add = 0;
#pragma unroll
    for (int j = 0; j < 4; j++) if (j < w) add += wsum[j];
    int excl = add + incl - v;
    if (t < 256) {
        cur[t] = excl;
        int gnode = b * BUCKET_W + t;
        if (gnode < N) {
            rowptr[gnode] = base + excl;
            dinv[gnode] = rsqrtf((float)(v + 1));
        }
    }
    if (b == NB - 1 && t == 0) rowptr[N] = base + cnt;
    __syncthreads();

    for (int i = t; i < cnt; i += 512) {
        unsigned int ev = eLDS[i];
        int dl = ev >> 17;
        int p = atomicAdd(&cur[dl], 1);
        col[base + p] = (int)(ev & 0x1FFFFu);
    }
}

// SCALE=1: g = (A@W)*dinv[row]; SCALE=0: g = A@W (dinv never read -> fusable)
template <int SCALE>
__device__ __forceinline__ void gemm_body(char* smem, int gb, int t,
                                          const unsigned short* __restrict__ A,
                                          const uint4* __restrict__ wimg,
                                          const float* __restrict__ dinv,
                                          unsigned short* __restrict__ g, int n) {
    uint4* Wl = (uint4*)smem;
    unsigned short* OutS = (unsigned short*)(smem + 32768);
    int lane = t & 63, wv = t >> 6;
    int blockRow = gb * 128;

    for (int idx = t; idx < 2048; idx += 512) Wl[idx] = wimg[idx];

    bf16x8 Af[4];
    {
        int arow = blockRow + wv * 16 + (lane & 15);
        const uint4* ap = (const uint4*)(A + (size_t)min(arow, n - 1) * 128);
#pragma unroll
        for (int s = 0; s < 4; s++) {
            uint4 u = ap[(lane >> 4) + s * 4];
            Af[s] = *(bf16x8*)&u;
        }
    }
    __syncthreads();

    f32x4 acc[8];
#pragma unroll
    for (int nt = 0; nt < 8; nt++) acc[nt] = (f32x4)(0.f);
#pragma unroll
    for (int s = 0; s < 4; s++) {
        int kb = s * 4 + (lane >> 4);
#pragma unroll
        for (int nt = 0; nt < 8; nt++) {
            int c = nt * 16 + (lane & 15);
            bf16x8 bh = *(bf16x8*)&Wl[c * 16 + (kb ^ (lane & 15))];
            acc[nt] = MF(Af[s], bh, acc[nt]);
        }
    }

    int rl0 = wv * 16 + (lane >> 4) * 4;
    float di[4];
#pragma unroll
    for (int r = 0; r < 4; r++)
        di[r] = SCALE ? dinv[min(blockRow + rl0 + r, n - 1)] : 1.f;
#pragma unroll
    for (int nt = 0; nt < 8; nt++) {
        int c = nt * 16 + (lane & 15);
#pragma unroll
        for (int r = 0; r < 4; r++)
            OutS[(rl0 + r) * OSTRIDE + c] = f2bf(acc[nt][r] * di[r]);
    }
    __syncthreads();
    {
        int row = t >> 2;
        int c0 = (t & 3) * 32;
        int grow = blockRow + row;
        if (grow < n) {
#pragma unroll
            for (int j = 0; j < 4; j++) {
                uint4 v = *(uint4*)&OutS[row * OSTRIDE + c0 + j * 8];
                *(uint4*)&g[(size_t)grow * 128 + c0 + j * 8] = v;
            }
        }
    }
}

__global__ __launch_bounds__(512)
void fg_kernel(const unsigned int* __restrict__ part, const int* __restrict__ bucketBase,
               int* __restrict__ rowptr, float* __restrict__ dinv, int* __restrict__ col,
               int N, int NB,
               const unsigned short* __restrict__ A, const uint4* __restrict__ wimg,
               unsigned short* __restrict__ g) {
    __shared__ __align__(16) char smem[67584];
    int b = blockIdx.x, t = threadIdx.x;
    if (b < NB) fill_body(smem, b, t, part, bucketBase, rowptr, dinv, col, N, NB);
    else        gemm_body<0>(smem, b - NB, t, A, wimg, (const float*)nullptr, g, N);
}

// ----------------------- standalone gemm (W2) ------------------------------
__global__ __launch_bounds__(512)
void gemm_bf16_kernel(const unsigned short* __restrict__ A, const uint4* __restrict__ wimg,
                      const float* __restrict__ dinv, unsigned short* __restrict__ g, int n) {
    __shared__ __align__(16) char smem[67584];
    gemm_body<1>(smem, blockIdx.x, threadIdx.x, A, wimg, dinv, g, n);
}

// ------------------------------ SpMM (bf16 g) ------------------------------
// XCD-sliced: combo = blockIdx&7 = (row-half<<2) | feature-slice.
// Block: 512 thr = 128 rows x 4 lanes; lane owns 8 feats (uint4).
// Per-edge request = 4 lanes x 16B = 64B line. Per-XCD gather stripe = 6.4MB.
// DVSRC=1: g unscaled; weight messages by dinv[src], self by dinv[i].
template <int RELU, int PACK, int DVSRC>
__global__ __launch_bounds__(512)
void spmm_kernel(const uint4* __restrict__ g16, const int* __restrict__ rowptr,
                 const int* __restrict__ col, const float* __restrict__ dinv,
                 const float* __restrict__ bias, void* __restrict__ outv,
                 int n, int halfN) {
    int combo = blockIdx.x & 7;
    int rb = blockIdx.x >> 3;
    int s = combo & 3;          // feature slice: feats [s*32, s*32+32)
    int rh = combo >> 2;        // row half
    int lr = rb * 128 + (threadIdx.x >> 2);
    if (lr >= halfN) return;
    int i = rh * halfN + lr;
    if (i >= n) return;
    int l4 = threadIdx.x & 3;
    int qoff = s * 4 + l4;      // uint4 index within 16-uint4 row

    float di = dinv[i];
    const uint4* gp = g16 + qoff;
    float acc[8];
    uint4 sv = gp[(size_t)i * 16];
    float wi = DVSRC ? di : 1.f;
    acc[0] = wi * blo(sv.x); acc[1] = wi * bhi(sv.x);
    acc[2] = wi * blo(sv.y); acc[3] = wi * bhi(sv.y);
    acc[4] = wi * blo(sv.z); acc[5] = wi * bhi(sv.z);
    acc[6] = wi * blo(sv.w); acc[7] = wi * bhi(sv.w);

    int e0 = rowptr[i], e1 = rowptr[i + 1];
    int e = e0;
    for (; e + 4 <= e1; e += 4) {
        int s0 = col[e], s1 = col[e + 1], s2 = col[e + 2], s3 = col[e + 3];
        uint4 v0 = gp[(size_t)s0 * 16];
        uint4 v1 = gp[(size_t)s1 * 16];
        uint4 v2 = gp[(size_t)s2 * 16];
        uint4 v3 = gp[(size_t)s3 * 16];
        float w0 = DVSRC ? dinv[s0] : 1.f;
        float w1 = DVSRC ? dinv[s1] : 1.f;
        float w2 = DVSRC ? dinv[s2] : 1.f;
        float w3 = DVSRC ? dinv[s3] : 1.f;
        acc[0] = fmaf(w0, blo(v0.x), fmaf(w1, blo(v1.x), fmaf(w2, blo(v2.x), fmaf(w3, blo(v3.x), acc[0]))));
        acc[1] = fmaf(w0, bhi(v0.x), fmaf(w1, bhi(v1.x), fmaf(w2, bhi(v2.x), fmaf(w3, bhi(v3.x), acc[1]))));
        acc[2] = fmaf(w0, blo(v0.y), fmaf(w1, blo(v1.y), fmaf(w2, blo(v2.y), fmaf(w3, blo(v3.y), acc[2]))));
        acc[3] = fmaf(w0, bhi(v0.y), fmaf(w1, bhi(v1.y), fmaf(w2, bhi(v2.y), fmaf(w3, bhi(v3.y), acc[3]))));
        acc[4] = fmaf(w0, blo(v0.z), fmaf(w1, blo(v1.z), fmaf(w2, blo(v2.z), fmaf(w3, blo(v3.z), acc[4]))));
        acc[5] = fmaf(w0, bhi(v0.z), fmaf(w1, bhi(v1.z), fmaf(w2, bhi(v2.z), fmaf(w3, bhi(v3.z), acc[5]))));
        acc[6] = fmaf(w0, blo(v0.w), fmaf(w1, blo(v1.w), fmaf(w2, blo(v2.w), fmaf(w3, blo(v3.w), acc[6]))));
        acc[7] = fmaf(w0, bhi(v0.w), fmaf(w1, bhi(v1.w), fmaf(w2, bhi(v2.w), fmaf(w3, bhi(v3.w), acc[7]))));
    }
    for (; e < e1; e++) {
        int s0 = col[e];
        uint4 v0 = gp[(size_t)s0 * 16];
        float w0 = DVSRC ? dinv[s0] : 1.f;
        acc[0] = fmaf(w0, blo(v0.x), acc[0]); acc[1] = fmaf(w0, bhi(v0.x), acc[1]);
        acc[2] = fmaf(w0, blo(v0.y), acc[2]); acc[3] = fmaf(w0, bhi(v0.y), acc[3]);
        acc[4] = fmaf(w0, blo(v0.z), acc[4]); acc[5] = fmaf(w0, bhi(v0.z), acc[5]);
        acc[6] = fmaf(w0, blo(v0.w), acc[6]); acc[7] = fmaf(w0, bhi(v0.w), acc[7]);
    }

    const float* bp = bias + s * 32 + l4 * 8;
    float4 bv0 = *(const float4*)&bp[0];
    float4 bv1 = *(const float4*)&bp[4];
    float r0[8];
    r0[0] = fmaf(acc[0], di, bv0.x);
    r0[1] = fmaf(acc[1], di, bv0.y);
    r0[2] = fmaf(acc[2], di, bv0.z);
    r0[3] = fmaf(acc[3], di, bv0.w);
    r0[4] = fmaf(acc[4], di, bv1.x);
    r0[5] = fmaf(acc[5], di, bv1.y);
    r0[6] = fmaf(acc[6], di, bv1.z);
    r0[7] = fmaf(acc[7], di, bv1.w);
    if (RELU) {
#pragma unroll
        for (int j = 0; j < 8; j++) r0[j] = fmaxf(r0[j], 0.f);
    }
    if (PACK) {
        uint4 w;
        w.x = (unsigned int)f2bf(r0[0]) | ((unsigned int)f2bf(r0[1]) << 16);
        w.y = (unsigned int)f2bf(r0[2]) | ((unsigned int)f2bf(r0[3]) << 16);
        w.z = (unsigned int)f2bf(r0[4]) | ((unsigned int)f2bf(r0[5]) << 16);
        w.w = (unsigned int)f2bf(r0[6]) | ((unsigned int)f2bf(r0[7]) << 16);
        *(uint4*)((unsigned short*)outv + (size_t)i * 128 + s * 32 + l4 * 8) = w;
    } else {
        float* o = (float*)outv + (size_t)i * 128 + s * 32 + l4 * 8;
        f32x4 a = *(f32x4*)&r0[0];
        f32x4 b = *(f32x4*)&r0[4];
        __builtin_nontemporal_store(a, (f32x4*)o);
        __builtin_nontemporal_store(b, (f32x4*)(o + 4));
    }
}

extern "C" void kernel_launch(void* const* d_in, const int* in_sizes, int n_in,
                              void* d_out, int out_size, void* d_ws, size_t ws_size,
                              hipStream_t stream) {
    const float* x      = (const float*)d_in[0];
    const int*   ei     = (const int*)d_in[1];
    const float* gate_W = (const float*)d_in[2];
    const float* gate_b = (const float*)d_in[3];
    const float* W1     = (const float*)d_in[4];
    const float* b1     = (const float*)d_in[5];
    const float* W2     = (const float*)d_in[6];
    const float* b2     = (const float*)d_in[7];
    float* out = (float*)d_out;

    const int N = in_sizes[0] / 128;
    const int E = in_sizes[1] / 2;
    const int* src = ei;
    const int* dst = ei + E;
    const int NB = (N + BUCKET_W - 1) / BUCKET_W;

    char* p = (char*)d_ws;
    auto alloc = [&](size_t bytes) { char* q = p; p += (bytes + 255) & ~(size_t)255; return q; };
    int*   rowptr  = (int*)alloc(((size_t)N + 1) * 4);
    float* dinv    = (float*)alloc((size_t)N * 4);
    int*   colb    = (int*)alloc((size_t)E * 4);
    int*   bcursor = (int*)alloc((size_t)NB * 4);
    int*   bbase   = (int*)alloc(((size_t)NB + 1) * 4);
    uint4* wimg    = (uint4*)alloc((size_t)3 * 2048 * 16);
    unsigned int*   part   = (unsigned int*)alloc((size_t)NB * CAP * 4);
    unsigned short* hpack  = (unsigned short*)alloc((size_t)N * 128 * 2);
    unsigned short* g16    = (unsigned short*)alloc((size_t)N * 128 * 2);
    unsigned short* h1pack = (unsigned short*)alloc((size_t)N * 128 * 2);

    const int pblocks = 256;
    const int chunk = (E + pblocks - 1) / pblocks;
    int gblocks = (N + 127) / 128;
    int halfN = (N + 1) / 2;
    int nrb = (halfN + 127) / 128;

    prepinit_kernel<<<13, 512, 0, stream>>>(gate_W, W1, W2, wimg, bcursor, NB);
    pg_kernel<<<256 + gblocks, 512, 0, stream>>>(src, dst, bcursor, part, E, NB, chunk,
                                                 x, wimg, gate_b, hpack, N);
    bucket_scan_kernel<<<1, 512, 0, stream>>>(bcursor, bbase, NB);
    fg_kernel<<<NB + gblocks, 512, 0, stream>>>(part, bbase, rowptr, dinv, colb, N, NB,
                                                hpack, wimg + 2048, g16);
    spmm_kernel<1, 1, 1><<<8 * nrb, 512, 0, stream>>>((const uint4*)g16, rowptr, colb,
                                                      dinv, b1, h1pack, N, halfN);
    gemm_bf16_kernel<<<gblocks, 512, 0, stream>>>(h1pack, wimg + 4096, dinv, g16, N);
    spmm_kernel<0, 0, 0><<<8 * nrb, 512, 0, stream>>>((const uint4*)g16, rowptr, colb,
                                                      dinv, b2, out, N, halfN);
}

// Round 11
// 212.175 us; speedup vs baseline: 1.5080x; 1.5080x over previous
//
#include <hip/hip_runtime.h>
#include <hip/hip_bf16.h>
#include <math.h>

// ---------------------------------------------------------------------------
// GCNEncoderWithGate R11:
//  - R10's XCD slicing REVERTED (64B requests -> 2x fetch amplification, 360MB).
//  - NEW: spmm1+gemm2 fused (spmm_gemm_kernel): block owns 64 full rows;
//    gather phase (256B/edge) -> h1 in LDS (bf16, swizzled A-tile) -> MFMA W2
//    -> g2 written directly. Kills h1 round-trip (52MB write + 26MB read) and
//    the spmm1 partial-line write amplification.
//  - spmm2 = R9 structure (temporal halves, NT fp32 stores).
// ---------------------------------------------------------------------------

#define BUCKET_SHIFT 8
#define BUCKET_W 256
#define CAP 4864
#define NB_MAX 512
#define OSTRIDE 136

typedef __attribute__((ext_vector_type(8))) short bf16x8;
typedef __attribute__((ext_vector_type(4))) float f32x4;

__device__ __forceinline__ unsigned short f2bf(float x) {
    unsigned int u = __float_as_uint(x);
    unsigned int r = (u + 0x7FFFu + ((u >> 16) & 1u)) >> 16;   // RNE
    return (unsigned short)r;
}
__device__ __forceinline__ float blo(unsigned int u) { return __uint_as_float(u << 16); }
__device__ __forceinline__ float bhi(unsigned int u) { return __uint_as_float(u & 0xFFFF0000u); }

__device__ __forceinline__ void cvt_hilo8(const float* v, bf16x8& hi, bf16x8& lo) {
#pragma unroll
    for (int j = 0; j < 8; j++) {
        unsigned short h = f2bf(v[j]);
        float hf = __uint_as_float((unsigned int)h << 16);
        hi[j] = (short)h;
        lo[j] = (short)f2bf(v[j] - hf);
    }
}

__device__ __forceinline__ f32x4 MF(bf16x8 a, bf16x8 b, f32x4 c) {
    return __builtin_amdgcn_mfma_f32_16x16x32_bf16(a, b, c, 0, 0, 0);
}

// ---------------------- prep weights + cursor init (1 dispatch) -------------
__global__ __launch_bounds__(512)
void prepinit_kernel(const float* __restrict__ W0, const float* __restrict__ W1,
                     const float* __restrict__ W2, uint4* __restrict__ img,
                     int* __restrict__ bcursor, int NB) {
    int b = blockIdx.x, t = threadIdx.x;
    if (b < 12) {
        int idx = b * 512 + t;            // 0..6143 = 3*2048
        int c = idx & 127, kb = (idx >> 7) & 15, w = idx >> 11;
        const float* W = (w == 0) ? W0 : (w == 1) ? W1 : W2;
        bf16x8 hb;
#pragma unroll
        for (int j = 0; j < 8; j++) hb[j] = (short)f2bf(W[(size_t)(kb * 8 + j) * 128 + c]);
        img[w * 2048 + c * 16 + (kb ^ (c & 15))] = *(uint4*)&hb;
    } else {
        if (t < NB) bcursor[t] = 0;
    }
}

// ---------------------- partition ∪ gate (1 dispatch) -----------------------
__device__ __forceinline__ void partition_body(char* smem, int b, int t,
                                               const int* __restrict__ src,
                                               const int* __restrict__ dst,
                                               int* __restrict__ bucketCursor,
                                               unsigned int* __restrict__ part,
                                               int E, int NB, int chunk) {
    int* hist  = (int*)smem;
    int* basec = hist + NB_MAX;
    int e0 = b * chunk;
    int e1 = min(E, e0 + chunk);

    for (int i = t; i < NB; i += 512) hist[i] = 0;
    __syncthreads();
    for (int e = e0 + t; e < e1; e += 512) {
        int bb = dst[e] >> BUCKET_SHIFT;
        atomicAdd(&hist[bb], 1);
    }
    __syncthreads();
    for (int i = t; i < NB; i += 512) {
        int c = hist[i];
        basec[i] = c ? atomicAdd(&bucketCursor[i], c) : 0;
    }
    __syncthreads();
    for (int i = t; i < NB; i += 512) hist[i] = 0;
    __syncthreads();
    for (int e = e0 + t; e < e1; e += 512) {
        int d = dst[e], s = src[e];
        int bb = d >> BUCKET_SHIFT;
        int r = atomicAdd(&hist[bb], 1);
        int pos = basec[bb] + r;
        if (pos < CAP)
            part[(size_t)bb * CAP + pos] = ((unsigned int)(d & (BUCKET_W - 1)) << 17) | (unsigned int)s;
    }
}

__device__ __forceinline__ void gate_body(char* smem, int gb, int t,
                                          const float* __restrict__ x,
                                          const uint4* __restrict__ gimg,
                                          const float* __restrict__ gate_b,
                                          unsigned short* __restrict__ hpack, int n) {
    uint4* Wl = (uint4*)smem;
    unsigned short* OutS = (unsigned short*)(smem + 32768);
    int lane = t & 63, wv = t >> 6;
    int blockRow = gb * 128;

    for (int idx = t; idx < 2048; idx += 512) Wl[idx] = gimg[idx];

    bf16x8 Ahi[4], Alo[4];
    {
        int arow = blockRow + wv * 16 + (lane & 15);
        const float* ap = x + (size_t)min(arow, n - 1) * 128 + (lane >> 4) * 8;
#pragma unroll
        for (int s = 0; s < 4; s++) {
            float v[8];
            *(float4*)&v[0] = *(const float4*)&ap[s * 32];
            *(float4*)&v[4] = *(const float4*)&ap[s * 32 + 4];
            cvt_hilo8(v, Ahi[s], Alo[s]);
        }
    }
    __syncthreads();

    f32x4 acc[8];
#pragma unroll
    for (int nt = 0; nt < 8; nt++) acc[nt] = (f32x4)(0.f);
#pragma unroll
    for (int s = 0; s < 4; s++) {
        int kb = s * 4 + (lane >> 4);
#pragma unroll
        for (int nt = 0; nt < 8; nt++) {
            int c = nt * 16 + (lane & 15);
            bf16x8 bh = *(bf16x8*)&Wl[c * 16 + (kb ^ (lane & 15))];
            acc[nt] = MF(Ahi[s], bh, acc[nt]);
            acc[nt] = MF(Alo[s], bh, acc[nt]);
        }
    }

    int rl0 = wv * 16 + (lane >> 4) * 4;
#pragma unroll
    for (int nt = 0; nt < 8; nt++) {
        int c = nt * 16 + (lane & 15);
        float gb2 = gate_b[c];
#pragma unroll
        for (int r = 0; r < 4; r++) {
            int grow = min(blockRow + rl0 + r, n - 1);
            float xv = x[(size_t)grow * 128 + c];
            float hv = xv / (1.f + __expf(-(acc[nt][r] + gb2)));
            OutS[(rl0 + r) * OSTRIDE + c] = f2bf(hv);
        }
    }
    __syncthreads();
    {
        int row = t >> 2;
        int c0 = (t & 3) * 32;
        int grow = blockRow + row;
        if (grow < n) {
#pragma unroll
            for (int j = 0; j < 4; j++) {
                uint4 v = *(uint4*)&OutS[row * OSTRIDE + c0 + j * 8];
                *(uint4*)&hpack[(size_t)grow * 128 + c0 + j * 8] = v;
            }
        }
    }
}

__global__ __launch_bounds__(512)
void pg_kernel(const int* __restrict__ src, const int* __restrict__ dst,
               int* __restrict__ bucketCursor, unsigned int* __restrict__ part,
               int E, int NB, int chunk,
               const float* __restrict__ x, const uint4* __restrict__ gimg,
               const float* __restrict__ gate_b, unsigned short* __restrict__ hpack, int n) {
    __shared__ __align__(16) char smem[67584];
    int b = blockIdx.x, t = threadIdx.x;
    if (b < 256) partition_body(smem, b, t, src, dst, bucketCursor, part, E, NB, chunk);
    else         gate_body(smem, b - 256, t, x, gimg, gate_b, hpack, n);
}

// ------------------------------ bucket scan --------------------------------
__global__ __launch_bounds__(512)
void bucket_scan_kernel(const int* __restrict__ bucketCursor,
                        int* __restrict__ bucketBase, int NB) {
    __shared__ int sm[NB_MAX];
    int t = threadIdx.x;
    int v = (t < NB) ? min(bucketCursor[t], CAP) : 0;
    sm[t] = v;
    __syncthreads();
    for (int off = 1; off < NB_MAX; off <<= 1) {
        int a = (t >= off) ? sm[t - off] : 0;
        __syncthreads();
        sm[t] += a;
        __syncthreads();
    }
    if (t < NB) bucketBase[t + 1] = sm[t];
    if (t == 0) bucketBase[0] = 0;
}

// ---------------------- bucket_fill ∪ gemm1 (1 dispatch) --------------------
__device__ __forceinline__ void fill_body(char* smem, int b, int t,
                                          const unsigned int* __restrict__ part,
                                          const int* __restrict__ bucketBase,
                                          int* __restrict__ rowptr, float* __restrict__ dinv,
                                          int* __restrict__ col, int N, int NB) {
    unsigned int* eLDS = (unsigned int*)smem;
    int* deg  = (int*)(smem + CAP * 4);
    int* cur  = deg + BUCKET_W;
    int* wsum = cur + BUCKET_W;   // 8 ints

    int base = bucketBase[b];
    int cnt = bucketBase[b + 1] - base;

    for (int i = t; i < cnt; i += 512) eLDS[i] = part[(size_t)b * CAP + i];
    if (t < 256) deg[t] = 0;
    __syncthreads();
    for (int i = t; i < cnt; i += 512) atomicAdd(&deg[eLDS[i] >> 17], 1);
    __syncthreads();

    int v = (t < 256) ? deg[t] : 0;
    int incl = v;
    int lane = t & 63, w = t >> 6;
    for (int off = 1; off < 64; off <<= 1) {
        int u = __shfl_up(incl, off, 64);
        if (lane >= off) incl += u;
    }
    if (lane == 63) wsum[w] = incl;
    __syncthreads();
    int add = 0;
#pragma unroll
    for (int j = 0; j < 4; j++) if (j < w) add += wsum[j];
    int excl = add + incl - v;
    if (t < 256) {
        cur[t] = excl;
        int gnode = b * BUCKET_W + t;
        if (gnode < N) {
            rowptr[gnode] = base + excl;
            dinv[gnode] = rsqrtf((float)(v + 1));
        }
    }
    if (b == NB - 1 && t == 0) rowptr[N] = base + cnt;
    __syncthreads();

    for (int i = t; i < cnt; i += 512) {
        unsigned int ev = eLDS[i];
        int dl = ev >> 17;
        int p = atomicAdd(&cur[dl], 1);
        col[base + p] = (int)(ev & 0x1FFFFu);
    }
}

// gemm1 (SCALE=0): G1 = A@W1 unscaled -> fusable with fill (no dinv read)
__device__ __forceinline__ void gemm_body(char* smem, int gb, int t,
                                          const unsigned short* __restrict__ A,
                                          const uint4* __restrict__ wimg,
                                          unsigned short* __restrict__ g, int n) {
    uint4* Wl = (uint4*)smem;
    unsigned short* OutS = (unsigned short*)(smem + 32768);
    int lane = t & 63, wv = t >> 6;
    int blockRow = gb * 128;

    for (int idx = t; idx < 2048; idx += 512) Wl[idx] = wimg[idx];

    bf16x8 Af[4];
    {
        int arow = blockRow + wv * 16 + (lane & 15);
        const uint4* ap = (const uint4*)(A + (size_t)min(arow, n - 1) * 128);
#pragma unroll
        for (int s = 0; s < 4; s++) {
            uint4 u = ap[(lane >> 4) + s * 4];
            Af[s] = *(bf16x8*)&u;
        }
    }
    __syncthreads();

    f32x4 acc[8];
#pragma unroll
    for (int nt = 0; nt < 8; nt++) acc[nt] = (f32x4)(0.f);
#pragma unroll
    for (int s = 0; s < 4; s++) {
        int kb = s * 4 + (lane >> 4);
#pragma unroll
        for (int nt = 0; nt < 8; nt++) {
            int c = nt * 16 + (lane & 15);
            bf16x8 bh = *(bf16x8*)&Wl[c * 16 + (kb ^ (lane & 15))];
            acc[nt] = MF(Af[s], bh, acc[nt]);
        }
    }

    int rl0 = wv * 16 + (lane >> 4) * 4;
#pragma unroll
    for (int nt = 0; nt < 8; nt++) {
        int c = nt * 16 + (lane & 15);
#pragma unroll
        for (int r = 0; r < 4; r++)
            OutS[(rl0 + r) * OSTRIDE + c] = f2bf(acc[nt][r]);
    }
    __syncthreads();
    {
        int row = t >> 2;
        int c0 = (t & 3) * 32;
        int grow = blockRow + row;
        if (grow < n) {
#pragma unroll
            for (int j = 0; j < 4; j++) {
                uint4 v = *(uint4*)&OutS[row * OSTRIDE + c0 + j * 8];
                *(uint4*)&g[(size_t)grow * 128 + c0 + j * 8] = v;
            }
        }
    }
}

__global__ __launch_bounds__(512)
void fg_kernel(const unsigned int* __restrict__ part, const int* __restrict__ bucketBase,
               int* __restrict__ rowptr, float* __restrict__ dinv, int* __restrict__ col,
               int N, int NB,
               const unsigned short* __restrict__ A, const uint4* __restrict__ wimg,
               unsigned short* __restrict__ g) {
    __shared__ __align__(16) char smem[67584];
    int b = blockIdx.x, t = threadIdx.x;
    if (b < NB) fill_body(smem, b, t, part, bucketBase, rowptr, dinv, col, N, NB);
    else        gemm_body(smem, b - NB, t, A, wimg, g, N);
}

// ------------------- fused spmm1 + gemm2 (1 dispatch) -----------------------
// Block owns 64 rows. Phase A (spmm): h1[i,:] = relu(di*(sum dinv[s]*G1[s] + di*G1[i]) + b1)
//   row r = t>>3, lane l = t&7 owns feats [l*8,+8) and [64+l*8,+8) (2 uint4/edge).
// Phase B (gemm): g2 = (h1 @ W2) * di via MFMA; h1 staged bf16 in LDS (swizzled).
__global__ __launch_bounds__(512)
void spmm_gemm_kernel(const uint4* __restrict__ g16, const int* __restrict__ rowptr,
                      const int* __restrict__ col, const float* __restrict__ dinv,
                      const float* __restrict__ b1, const uint4* __restrict__ w2img,
                      unsigned short* __restrict__ g2, int n) {
    __shared__ __align__(16) char smem[49664];
    uint4* W2l = (uint4*)smem;                      // 32 KB (aliased by OutS later)
    uint4* Hl  = (uint4*)(smem + 32768);            // 64 rows x 16 uint4 = 16 KB
    float* dl  = (float*)(smem + 49152);            // 64 floats
    unsigned short* OutS = (unsigned short*)smem;   // [64][OSTRIDE] aliases W2l

    int t = threadIdx.x;
    int blockRow = blockIdx.x * 64;

    for (int idx = t; idx < 2048; idx += 512) W2l[idx] = w2img[idx];

    // ---- Phase A: spmm ----
    int r = t >> 3, l = t & 7;
    int i = min(blockRow + r, n - 1);
    float di = dinv[i];
    if (l == 0) dl[r] = di;

    float acc[16];
    {
        uint4 s0 = g16[(size_t)i * 16 + l];
        uint4 s1 = g16[(size_t)i * 16 + 8 + l];
        acc[0] = di * blo(s0.x);  acc[1] = di * bhi(s0.x);
        acc[2] = di * blo(s0.y);  acc[3] = di * bhi(s0.y);
        acc[4] = di * blo(s0.z);  acc[5] = di * bhi(s0.z);
        acc[6] = di * blo(s0.w);  acc[7] = di * bhi(s0.w);
        acc[8] = di * blo(s1.x);  acc[9] = di * bhi(s1.x);
        acc[10] = di * blo(s1.y); acc[11] = di * bhi(s1.y);
        acc[12] = di * blo(s1.z); acc[13] = di * bhi(s1.z);
        acc[14] = di * blo(s1.w); acc[15] = di * bhi(s1.w);
    }
    int e0 = rowptr[i], e1 = rowptr[i + 1];
    int e = e0;
    for (; e + 2 <= e1; e += 2) {
        int s0 = col[e], s1 = col[e + 1];
        uint4 a0 = g16[(size_t)s0 * 16 + l];
        uint4 a1 = g16[(size_t)s0 * 16 + 8 + l];
        uint4 c0 = g16[(size_t)s1 * 16 + l];
        uint4 c1 = g16[(size_t)s1 * 16 + 8 + l];
        float w0 = dinv[s0], w1 = dinv[s1];
        acc[0]  = fmaf(w0, blo(a0.x), fmaf(w1, blo(c0.x), acc[0]));
        acc[1]  = fmaf(w0, bhi(a0.x), fmaf(w1, bhi(c0.x), acc[1]));
        acc[2]  = fmaf(w0, blo(a0.y), fmaf(w1, blo(c0.y), acc[2]));
        acc[3]  = fmaf(w0, bhi(a0.y), fmaf(w1, bhi(c0.y), acc[3]));
        acc[4]  = fmaf(w0, blo(a0.z), fmaf(w1, blo(c0.z), acc[4]));
        acc[5]  = fmaf(w0, bhi(a0.z), fmaf(w1, bhi(c0.z), acc[5]));
        acc[6]  = fmaf(w0, blo(a0.w), fmaf(w1, blo(c0.w), acc[6]));
        acc[7]  = fmaf(w0, bhi(a0.w), fmaf(w1, bhi(c0.w), acc[7]));
        acc[8]  = fmaf(w0, blo(a1.x), fmaf(w1, blo(c1.x), acc[8]));
        acc[9]  = fmaf(w0, bhi(a1.x), fmaf(w1, bhi(c1.x), acc[9]));
        acc[10] = fmaf(w0, blo(a1.y), fmaf(w1, blo(c1.y), acc[10]));
        acc[11] = fmaf(w0, bhi(a1.y), fmaf(w1, bhi(c1.y), acc[11]));
        acc[12] = fmaf(w0, blo(a1.z), fmaf(w1, blo(c1.z), acc[12]));
        acc[13] = fmaf(w0, bhi(a1.z), fmaf(w1, bhi(c1.z), acc[13]));
        acc[14] = fmaf(w0, blo(a1.w), fmaf(w1, blo(c1.w), acc[14]));
        acc[15] = fmaf(w0, bhi(a1.w), fmaf(w1, bhi(c1.w), acc[15]));
    }
    if (e < e1) {
        int s0 = col[e];
        uint4 a0 = g16[(size_t)s0 * 16 + l];
        uint4 a1 = g16[(size_t)s0 * 16 + 8 + l];
        float w0 = dinv[s0];
        acc[0]  = fmaf(w0, blo(a0.x), acc[0]);  acc[1]  = fmaf(w0, bhi(a0.x), acc[1]);
        acc[2]  = fmaf(w0, blo(a0.y), acc[2]);  acc[3]  = fmaf(w0, bhi(a0.y), acc[3]);
        acc[4]  = fmaf(w0, blo(a0.z), acc[4]);  acc[5]  = fmaf(w0, bhi(a0.z), acc[5]);
        acc[6]  = fmaf(w0, blo(a0.w), acc[6]);  acc[7]  = fmaf(w0, bhi(a0.w), acc[7]);
        acc[8]  = fmaf(w0, blo(a1.x), acc[8]);  acc[9]  = fmaf(w0, bhi(a1.x), acc[9]);
        acc[10] = fmaf(w0, blo(a1.y), acc[10]); acc[11] = fmaf(w0, bhi(a1.y), acc[11]);
        acc[12] = fmaf(w0, blo(a1.z), acc[12]); acc[13] = fmaf(w0, bhi(a1.z), acc[13]);
        acc[14] = fmaf(w0, blo(a1.w), acc[14]); acc[15] = fmaf(w0, bhi(a1.w), acc[15]);
    }

    // h1 = relu(acc*di + b1); pack bf16 -> Hl (kb ^ (row&15) swizzle)
    {
        const float* bp0 = b1 + l * 8;
        const float* bp1 = b1 + 64 + l * 8;
        float4 b00 = *(const float4*)&bp0[0], b01 = *(const float4*)&bp0[4];
        float4 b10 = *(const float4*)&bp1[0], b11 = *(const float4*)&bp1[4];
        float h[16];
        h[0] = fmaxf(fmaf(acc[0], di, b00.x), 0.f);
        h[1] = fmaxf(fmaf(acc[1], di, b00.y), 0.f);
        h[2] = fmaxf(fmaf(acc[2], di, b00.z), 0.f);
        h[3] = fmaxf(fmaf(acc[3], di, b00.w), 0.f);
        h[4] = fmaxf(fmaf(acc[4], di, b01.x), 0.f);
        h[5] = fmaxf(fmaf(acc[5], di, b01.y), 0.f);
        h[6] = fmaxf(fmaf(acc[6], di, b01.z), 0.f);
        h[7] = fmaxf(fmaf(acc[7], di, b01.w), 0.f);
        h[8] = fmaxf(fmaf(acc[8], di, b10.x), 0.f);
        h[9] = fmaxf(fmaf(acc[9], di, b10.y), 0.f);
        h[10] = fmaxf(fmaf(acc[10], di, b10.z), 0.f);
        h[11] = fmaxf(fmaf(acc[11], di, b10.w), 0.f);
        h[12] = fmaxf(fmaf(acc[12], di, b11.x), 0.f);
        h[13] = fmaxf(fmaf(acc[13], di, b11.y), 0.f);
        h[14] = fmaxf(fmaf(acc[14], di, b11.z), 0.f);
        h[15] = fmaxf(fmaf(acc[15], di, b11.w), 0.f);
        uint4 p0, p1;
        p0.x = (unsigned int)f2bf(h[0]) | ((unsigned int)f2bf(h[1]) << 16);
        p0.y = (unsigned int)f2bf(h[2]) | ((unsigned int)f2bf(h[3]) << 16);
        p0.z = (unsigned int)f2bf(h[4]) | ((unsigned int)f2bf(h[5]) << 16);
        p0.w = (unsigned int)f2bf(h[6]) | ((unsigned int)f2bf(h[7]) << 16);
        p1.x = (unsigned int)f2bf(h[8]) | ((unsigned int)f2bf(h[9]) << 16);
        p1.y = (unsigned int)f2bf(h[10]) | ((unsigned int)f2bf(h[11]) << 16);
        p1.z = (unsigned int)f2bf(h[12]) | ((unsigned int)f2bf(h[13]) << 16);
        p1.w = (unsigned int)f2bf(h[14]) | ((unsigned int)f2bf(h[15]) << 16);
        int sw = r & 15;
        Hl[r * 16 + (l ^ sw)] = p0;
        Hl[r * 16 + ((l + 8) ^ sw)] = p1;
    }
    __syncthreads();

    // ---- Phase B: gemm2 via MFMA. wave wv: row-tile rt = wv&3, col-half ch = wv>>2
    int lane = t & 63, wv = t >> 6;
    int rt = wv & 3, ch = wv >> 2;
    bf16x8 Af[4];
    {
        int arow = rt * 16 + (lane & 15);
        int asw = arow & 15;
#pragma unroll
        for (int s = 0; s < 4; s++) {
            int kb = s * 4 + (lane >> 4);
            uint4 u = Hl[arow * 16 + (kb ^ asw)];
            Af[s] = *(bf16x8*)&u;
        }
    }
    f32x4 acc2[4];
#pragma unroll
    for (int ntl = 0; ntl < 4; ntl++) acc2[ntl] = (f32x4)(0.f);
#pragma unroll
    for (int s = 0; s < 4; s++) {
        int kb = s * 4 + (lane >> 4);
#pragma unroll
        for (int ntl = 0; ntl < 4; ntl++) {
            int c = (ch * 4 + ntl) * 16 + (lane & 15);
            bf16x8 bh = *(bf16x8*)&W2l[c * 16 + (kb ^ (lane & 15))];
            acc2[ntl] = MF(Af[s], bh, acc2[ntl]);
        }
    }

    int rl0 = rt * 16 + (lane >> 4) * 4;
    float dr[4];
#pragma unroll
    for (int rr = 0; rr < 4; rr++) dr[rr] = dl[rl0 + rr];
    __syncthreads();   // all W2l reads done before OutS aliases it
#pragma unroll
    for (int ntl = 0; ntl < 4; ntl++) {
        int c = (ch * 4 + ntl) * 16 + (lane & 15);
#pragma unroll
        for (int rr = 0; rr < 4; rr++)
            OutS[(rl0 + rr) * OSTRIDE + c] = f2bf(acc2[ntl][rr] * dr[rr]);
    }
    __syncthreads();
    {
        int grow = blockRow + r;
        if (grow < n) {
            uint4 v0 = *(uint4*)&OutS[r * OSTRIDE + l * 16];
            uint4 v1 = *(uint4*)&OutS[r * OSTRIDE + l * 16 + 8];
            *(uint4*)&g2[(size_t)grow * 128 + l * 16] = v0;
            *(uint4*)&g2[(size_t)grow * 128 + l * 16 + 8] = v1;
        }
    }
}

// ------------------------------ SpMM (R9 structure) -------------------------
// Feature-split halves: blocks [0,nhb) feats [0,64), [nhb,2nhb) feats [64,128).
// g pre-scaled (dinv[src] already applied via gemm SCALE or fused epilogue).
__global__ void spmm_kernel(const uint4* __restrict__ g16, const int* __restrict__ rowptr,
                            const int* __restrict__ col, const float* __restrict__ dinv,
                            const float* __restrict__ bias, float* __restrict__ outv,
                            int n, int nhb) {
    int half = (blockIdx.x >= nhb) ? 1 : 0;
    int rb = blockIdx.x - half * nhb;
    int i = rb * 32 + (threadIdx.x >> 3);
    if (i >= n) return;
    int c = threadIdx.x & 7;

    const uint4* gp = g16 + half * 8 + c;
    float acc[8];
    uint4 sv = gp[(size_t)i * 16];
    acc[0] = blo(sv.x); acc[1] = bhi(sv.x);
    acc[2] = blo(sv.y); acc[3] = bhi(sv.y);
    acc[4] = blo(sv.z); acc[5] = bhi(sv.z);
    acc[6] = blo(sv.w); acc[7] = bhi(sv.w);

    int e0 = rowptr[i], e1 = rowptr[i + 1];
    int e = e0;
    for (; e + 4 <= e1; e += 4) {
        int s0 = col[e], s1 = col[e + 1], s2 = col[e + 2], s3 = col[e + 3];
        uint4 v0 = gp[(size_t)s0 * 16];
        uint4 v1 = gp[(size_t)s1 * 16];
        uint4 v2 = gp[(size_t)s2 * 16];
        uint4 v3 = gp[(size_t)s3 * 16];
        acc[0] += (blo(v0.x) + blo(v1.x)) + (blo(v2.x) + blo(v3.x));
        acc[1] += (bhi(v0.x) + bhi(v1.x)) + (bhi(v2.x) + bhi(v3.x));
        acc[2] += (blo(v0.y) + blo(v1.y)) + (blo(v2.y) + blo(v3.y));
        acc[3] += (bhi(v0.y) + bhi(v1.y)) + (bhi(v2.y) + bhi(v3.y));
        acc[4] += (blo(v0.z) + blo(v1.z)) + (blo(v2.z) + blo(v3.z));
        acc[5] += (bhi(v0.z) + bhi(v1.z)) + (bhi(v2.z) + bhi(v3.z));
        acc[6] += (blo(v0.w) + blo(v1.w)) + (blo(v2.w) + blo(v3.w));
        acc[7] += (bhi(v0.w) + bhi(v1.w)) + (bhi(v2.w) + bhi(v3.w));
    }
    for (; e < e1; e++) {
        int s0 = col[e];
        uint4 v0 = gp[(size_t)s0 * 16];
        acc[0] += blo(v0.x); acc[1] += bhi(v0.x);
        acc[2] += blo(v0.y); acc[3] += bhi(v0.y);
        acc[4] += blo(v0.z); acc[5] += bhi(v0.z);
        acc[6] += blo(v0.w); acc[7] += bhi(v0.w);
    }

    float di = dinv[i];
    const float4* b4 = (const float4*)(bias + half * 64);
    float4 bv0 = b4[c * 2], bv1 = b4[c * 2 + 1];
    float r0[8];
    r0[0] = fmaf(acc[0], di, bv0.x);
    r0[1] = fmaf(acc[1], di, bv0.y);
    r0[2] = fmaf(acc[2], di, bv0.z);
    r0[3] = fmaf(acc[3], di, bv0.w);
    r0[4] = fmaf(acc[4], di, bv1.x);
    r0[5] = fmaf(acc[5], di, bv1.y);
    r0[6] = fmaf(acc[6], di, bv1.z);
    r0[7] = fmaf(acc[7], di, bv1.w);
    float* o = outv + (size_t)i * 128 + half * 64 + c * 8;
    f32x4 a = *(f32x4*)&r0[0];
    f32x4 b = *(f32x4*)&r0[4];
    __builtin_nontemporal_store(a, (f32x4*)o);
    __builtin_nontemporal_store(b, (f32x4*)(o + 4));
}

extern "C" void kernel_launch(void* const* d_in, const int* in_sizes, int n_in,
                              void* d_out, int out_size, void* d_ws, size_t ws_size,
                              hipStream_t stream) {
    const float* x      = (const float*)d_in[0];
    const int*   ei     = (const int*)d_in[1];
    const float* gate_W = (const float*)d_in[2];
    const float* gate_b = (const float*)d_in[3];
    const float* W1     = (const float*)d_in[4];
    const float* b1     = (const float*)d_in[5];
    const float* W2     = (const float*)d_in[6];
    const float* b2     = (const float*)d_in[7];
    float* out = (float*)d_out;

    const int N = in_sizes[0] / 128;
    const int E = in_sizes[1] / 2;
    const int* src = ei;
    const int* dst = ei + E;
    const int NB = (N + BUCKET_W - 1) / BUCKET_W;

    char* p = (char*)d_ws;
    auto alloc = [&](size_t bytes) { char* q = p; p += (bytes + 255) & ~(size_t)255; return q; };
    int*   rowptr  = (int*)alloc(((size_t)N + 1) * 4);
    float* dinv    = (float*)alloc((size_t)N * 4);
    int*   colb    = (int*)alloc((size_t)E * 4);
    int*   bcursor = (int*)alloc((size_t)NB * 4);
    int*   bbase   = (int*)alloc(((size_t)NB + 1) * 4);
    uint4* wimg    = (uint4*)alloc((size_t)3 * 2048 * 16);
    unsigned int*   part   = (unsigned int*)alloc((size_t)NB * CAP * 4);
    unsigned short* hpack  = (unsigned short*)alloc((size_t)N * 128 * 2);
    unsigned short* g16    = (unsigned short*)alloc((size_t)N * 128 * 2);
    unsigned short* g2buf  = (unsigned short*)alloc((size_t)N * 128 * 2);

    const int pblocks = 256;
    const int chunk = (E + pblocks - 1) / pblocks;
    int gblocks = (N + 127) / 128;
    int fblocks = (N + 63) / 64;
    int nhb = (N + 31) / 32;

    prepinit_kernel<<<13, 512, 0, stream>>>(gate_W, W1, W2, wimg, bcursor, NB);
    pg_kernel<<<256 + gblocks, 512, 0, stream>>>(src, dst, bcursor, part, E, NB, chunk,
                                                 x, wimg, gate_b, hpack, N);
    bucket_scan_kernel<<<1, 512, 0, stream>>>(bcursor, bbase, NB);
    fg_kernel<<<NB + gblocks, 512, 0, stream>>>(part, bbase, rowptr, dinv, colb, N, NB,
                                                hpack, wimg + 2048, g16);
    spmm_gemm_kernel<<<fblocks, 512, 0, stream>>>((const uint4*)g16, rowptr, colb,
                                                  dinv, b1, wimg + 4096, g2buf, N);
    spmm_kernel<<<2 * nhb, 256, 0, stream>>>((const uint4*)g2buf, rowptr, colb,
                                             dinv, b2, out, N, nhb);
}

// Round 12
// 209.357 us; speedup vs baseline: 1.5283x; 1.0135x over previous
//
#include <hip/hip_runtime.h>
#include <hip/hip_bf16.h>
#include <math.h>

// ---------------------------------------------------------------------------
// GCNEncoderWithGate R12 (= R11 with spmm granularity fixes):
//  - spmm_gemm: 32 rows/block, 256 thr, LDS 40960 (W2 32K + Hl 8K, no dl)
//    -> 4 blocks/CU, 3125 blocks (even rounds, small tails); gather unroll 4.
//  - spmm2: edge-loop unroll 8 (more MLP).
//  - everything else identical to R11.
// ---------------------------------------------------------------------------

#define BUCKET_SHIFT 8
#define BUCKET_W 256
#define CAP 4864
#define NB_MAX 512
#define OSTRIDE 136

typedef __attribute__((ext_vector_type(8))) short bf16x8;
typedef __attribute__((ext_vector_type(4))) float f32x4;

__device__ __forceinline__ unsigned short f2bf(float x) {
    unsigned int u = __float_as_uint(x);
    unsigned int r = (u + 0x7FFFu + ((u >> 16) & 1u)) >> 16;   // RNE
    return (unsigned short)r;
}
__device__ __forceinline__ float blo(unsigned int u) { return __uint_as_float(u << 16); }
__device__ __forceinline__ float bhi(unsigned int u) { return __uint_as_float(u & 0xFFFF0000u); }

__device__ __forceinline__ void cvt_hilo8(const float* v, bf16x8& hi, bf16x8& lo) {
#pragma unroll
    for (int j = 0; j < 8; j++) {
        unsigned short h = f2bf(v[j]);
        float hf = __uint_as_float((unsigned int)h << 16);
        hi[j] = (short)h;
        lo[j] = (short)f2bf(v[j] - hf);
    }
}

__device__ __forceinline__ f32x4 MF(bf16x8 a, bf16x8 b, f32x4 c) {
    return __builtin_amdgcn_mfma_f32_16x16x32_bf16(a, b, c, 0, 0, 0);
}

// ---------------------- prep weights + cursor init (1 dispatch) -------------
__global__ __launch_bounds__(512)
void prepinit_kernel(const float* __restrict__ W0, const float* __restrict__ W1,
                     const float* __restrict__ W2, uint4* __restrict__ img,
                     int* __restrict__ bcursor, int NB) {
    int b = blockIdx.x, t = threadIdx.x;
    if (b < 12) {
        int idx = b * 512 + t;            // 0..6143 = 3*2048
        int c = idx & 127, kb = (idx >> 7) & 15, w = idx >> 11;
        const float* W = (w == 0) ? W0 : (w == 1) ? W1 : W2;
        bf16x8 hb;
#pragma unroll
        for (int j = 0; j < 8; j++) hb[j] = (short)f2bf(W[(size_t)(kb * 8 + j) * 128 + c]);
        img[w * 2048 + c * 16 + (kb ^ (c & 15))] = *(uint4*)&hb;
    } else {
        if (t < NB) bcursor[t] = 0;
    }
}

// ---------------------- partition ∪ gate (1 dispatch) -----------------------
__device__ __forceinline__ void partition_body(char* smem, int b, int t,
                                               const int* __restrict__ src,
                                               const int* __restrict__ dst,
                                               int* __restrict__ bucketCursor,
                                               unsigned int* __restrict__ part,
                                               int E, int NB, int chunk) {
    int* hist  = (int*)smem;
    int* basec = hist + NB_MAX;
    int e0 = b * chunk;
    int e1 = min(E, e0 + chunk);

    for (int i = t; i < NB; i += 512) hist[i] = 0;
    __syncthreads();
    for (int e = e0 + t; e < e1; e += 512) {
        int bb = dst[e] >> BUCKET_SHIFT;
        atomicAdd(&hist[bb], 1);
    }
    __syncthreads();
    for (int i = t; i < NB; i += 512) {
        int c = hist[i];
        basec[i] = c ? atomicAdd(&bucketCursor[i], c) : 0;
    }
    __syncthreads();
    for (int i = t; i < NB; i += 512) hist[i] = 0;
    __syncthreads();
    for (int e = e0 + t; e < e1; e += 512) {
        int d = dst[e], s = src[e];
        int bb = d >> BUCKET_SHIFT;
        int r = atomicAdd(&hist[bb], 1);
        int pos = basec[bb] + r;
        if (pos < CAP)
            part[(size_t)bb * CAP + pos] = ((unsigned int)(d & (BUCKET_W - 1)) << 17) | (unsigned int)s;
    }
}

__device__ __forceinline__ void gate_body(char* smem, int gb, int t,
                                          const float* __restrict__ x,
                                          const uint4* __restrict__ gimg,
                                          const float* __restrict__ gate_b,
                                          unsigned short* __restrict__ hpack, int n) {
    uint4* Wl = (uint4*)smem;
    unsigned short* OutS = (unsigned short*)(smem + 32768);
    int lane = t & 63, wv = t >> 6;
    int blockRow = gb * 128;

    for (int idx = t; idx < 2048; idx += 512) Wl[idx] = gimg[idx];

    bf16x8 Ahi[4], Alo[4];
    {
        int arow = blockRow + wv * 16 + (lane & 15);
        const float* ap = x + (size_t)min(arow, n - 1) * 128 + (lane >> 4) * 8;
#pragma unroll
        for (int s = 0; s < 4; s++) {
            float v[8];
            *(float4*)&v[0] = *(const float4*)&ap[s * 32];
            *(float4*)&v[4] = *(const float4*)&ap[s * 32 + 4];
            cvt_hilo8(v, Ahi[s], Alo[s]);
        }
    }
    __syncthreads();

    f32x4 acc[8];
#pragma unroll
    for (int nt = 0; nt < 8; nt++) acc[nt] = (f32x4)(0.f);
#pragma unroll
    for (int s = 0; s < 4; s++) {
        int kb = s * 4 + (lane >> 4);
#pragma unroll
        for (int nt = 0; nt < 8; nt++) {
            int c = nt * 16 + (lane & 15);
            bf16x8 bh = *(bf16x8*)&Wl[c * 16 + (kb ^ (lane & 15))];
            acc[nt] = MF(Ahi[s], bh, acc[nt]);
            acc[nt] = MF(Alo[s], bh, acc[nt]);
        }
    }

    int rl0 = wv * 16 + (lane >> 4) * 4;
#pragma unroll
    for (int nt = 0; nt < 8; nt++) {
        int c = nt * 16 + (lane & 15);
        float gb2 = gate_b[c];
#pragma unroll
        for (int r = 0; r < 4; r++) {
            int grow = min(blockRow + rl0 + r, n - 1);
            float xv = x[(size_t)grow * 128 + c];
            float hv = xv / (1.f + __expf(-(acc[nt][r] + gb2)));
            OutS[(rl0 + r) * OSTRIDE + c] = f2bf(hv);
        }
    }
    __syncthreads();
    {
        int row = t >> 2;
        int c0 = (t & 3) * 32;
        int grow = blockRow + row;
        if (grow < n) {
#pragma unroll
            for (int j = 0; j < 4; j++) {
                uint4 v = *(uint4*)&OutS[row * OSTRIDE + c0 + j * 8];
                *(uint4*)&hpack[(size_t)grow * 128 + c0 + j * 8] = v;
            }
        }
    }
}

__global__ __launch_bounds__(512)
void pg_kernel(const int* __restrict__ src, const int* __restrict__ dst,
               int* __restrict__ bucketCursor, unsigned int* __restrict__ part,
               int E, int NB, int chunk,
               const float* __restrict__ x, const uint4* __restrict__ gimg,
               const float* __restrict__ gate_b, unsigned short* __restrict__ hpack, int n) {
    __shared__ __align__(16) char smem[67584];
    int b = blockIdx.x, t = threadIdx.x;
    if (b < 256) partition_body(smem, b, t, src, dst, bucketCursor, part, E, NB, chunk);
    else         gate_body(smem, b - 256, t, x, gimg, gate_b, hpack, n);
}

// ------------------------------ bucket scan --------------------------------
__global__ __launch_bounds__(512)
void bucket_scan_kernel(const int* __restrict__ bucketCursor,
                        int* __restrict__ bucketBase, int NB) {
    __shared__ int sm[NB_MAX];
    int t = threadIdx.x;
    int v = (t < NB) ? min(bucketCursor[t], CAP) : 0;
    sm[t] = v;
    __syncthreads();
    for (int off = 1; off < NB_MAX; off <<= 1) {
        int a = (t >= off) ? sm[t - off] : 0;
        __syncthreads();
        sm[t] += a;
        __syncthreads();
    }
    if (t < NB) bucketBase[t + 1] = sm[t];
    if (t == 0) bucketBase[0] = 0;
}

// ---------------------- bucket_fill ∪ gemm1 (1 dispatch) --------------------
__device__ __forceinline__ void fill_body(char* smem, int b, int t,
                                          const unsigned int* __restrict__ part,
                                          const int* __restrict__ bucketBase,
                                          int* __restrict__ rowptr, float* __restrict__ dinv,
                                          int* __restrict__ col, int N, int NB) {
    unsigned int* eLDS = (unsigned int*)smem;
    int* deg  = (int*)(smem + CAP * 4);
    int* cur  = deg + BUCKET_W;
    int* wsum = cur + BUCKET_W;   // 8 ints

    int base = bucketBase[b];
    int cnt = bucketBase[b + 1] - base;

    for (int i = t; i < cnt; i += 512) eLDS[i] = part[(size_t)b * CAP + i];
    if (t < 256) deg[t] = 0;
    __syncthreads();
    for (int i = t; i < cnt; i += 512) atomicAdd(&deg[eLDS[i] >> 17], 1);
    __syncthreads();

    int v = (t < 256) ? deg[t] : 0;
    int incl = v;
    int lane = t & 63, w = t >> 6;
    for (int off = 1; off < 64; off <<= 1) {
        int u = __shfl_up(incl, off, 64);
        if (lane >= off) incl += u;
    }
    if (lane == 63) wsum[w] = incl;
    __syncthreads();
    int add = 0;
#pragma unroll
    for (int j = 0; j < 4; j++) if (j < w) add += wsum[j];
    int excl = add + incl - v;
    if (t < 256) {
        cur[t] = excl;
        int gnode = b * BUCKET_W + t;
        if (gnode < N) {
            rowptr[gnode] = base + excl;
            dinv[gnode] = rsqrtf((float)(v + 1));
        }
    }
    if (b == NB - 1 && t == 0) rowptr[N] = base + cnt;
    __syncthreads();

    for (int i = t; i < cnt; i += 512) {
        unsigned int ev = eLDS[i];
        int dl = ev >> 17;
        int p = atomicAdd(&cur[dl], 1);
        col[base + p] = (int)(ev & 0x1FFFFu);
    }
}

// gemm1 (SCALE=0): G1 = A@W1 unscaled -> fusable with fill (no dinv read)
__device__ __forceinline__ void gemm_body(char* smem, int gb, int t,
                                          const unsigned short* __restrict__ A,
                                          const uint4* __restrict__ wimg,
                                          unsigned short* __restrict__ g, int n) {
    uint4* Wl = (uint4*)smem;
    unsigned short* OutS = (unsigned short*)(smem + 32768);
    int lane = t & 63, wv = t >> 6;
    int blockRow = gb * 128;

    for (int idx = t; idx < 2048; idx += 512) Wl[idx] = wimg[idx];

    bf16x8 Af[4];
    {
        int arow = blockRow + wv * 16 + (lane & 15);
        const uint4* ap = (const uint4*)(A + (size_t)min(arow, n - 1) * 128);
#pragma unroll
        for (int s = 0; s < 4; s++) {
            uint4 u = ap[(lane >> 4) + s * 4];
            Af[s] = *(bf16x8*)&u;
        }
    }
    __syncthreads();

    f32x4 acc[8];
#pragma unroll
    for (int nt = 0; nt < 8; nt++) acc[nt] = (f32x4)(0.f);
#pragma unroll
    for (int s = 0; s < 4; s++) {
        int kb = s * 4 + (lane >> 4);
#pragma unroll
        for (int nt = 0; nt < 8; nt++) {
            int c = nt * 16 + (lane & 15);
            bf16x8 bh = *(bf16x8*)&Wl[c * 16 + (kb ^ (lane & 15))];
            acc[nt] = MF(Af[s], bh, acc[nt]);
        }
    }

    int rl0 = wv * 16 + (lane >> 4) * 4;
#pragma unroll
    for (int nt = 0; nt < 8; nt++) {
        int c = nt * 16 + (lane & 15);
#pragma unroll
        for (int r = 0; r < 4; r++)
            OutS[(rl0 + r) * OSTRIDE + c] = f2bf(acc[nt][r]);
    }
    __syncthreads();
    {
        int row = t >> 2;
        int c0 = (t & 3) * 32;
        int grow = blockRow + row;
        if (grow < n) {
#pragma unroll
            for (int j = 0; j < 4; j++) {
                uint4 v = *(uint4*)&OutS[row * OSTRIDE + c0 + j * 8];
                *(uint4*)&g[(size_t)grow * 128 + c0 + j * 8] = v;
            }
        }
    }
}

__global__ __launch_bounds__(512)
void fg_kernel(const unsigned int* __restrict__ part, const int* __restrict__ bucketBase,
               int* __restrict__ rowptr, float* __restrict__ dinv, int* __restrict__ col,
               int N, int NB,
               const unsigned short* __restrict__ A, const uint4* __restrict__ wimg,
               unsigned short* __restrict__ g) {
    __shared__ __align__(16) char smem[67584];
    int b = blockIdx.x, t = threadIdx.x;
    if (b < NB) fill_body(smem, b, t, part, bucketBase, rowptr, dinv, col, N, NB);
    else        gemm_body(smem, b - NB, t, A, wimg, g, N);
}

// ------------------- fused spmm1 + gemm2 (1 dispatch) -----------------------
// 32 rows/block, 256 thr, LDS 40960 = W2l 32K + Hl 8K -> 4 blocks/CU.
// Phase A: h1 = relu(di*(sum dinv[s]*G1[s] + di*G1[i]) + b1)  (unroll 4)
// Phase B: g2 = (h1 @ W2) * di via MFMA (4 waves: 2 row-tiles x 2 col-halves).
__global__ __launch_bounds__(256)
void spmm_gemm_kernel(const uint4* __restrict__ g16, const int* __restrict__ rowptr,
                      const int* __restrict__ col, const float* __restrict__ dinv,
                      const float* __restrict__ b1, const uint4* __restrict__ w2img,
                      unsigned short* __restrict__ g2, int n) {
    __shared__ __align__(16) char smem[40960];
    uint4* W2l = (uint4*)smem;                      // 32 KB (aliased by OutS later)
    uint4* Hl  = (uint4*)(smem + 32768);            // 32 rows x 16 uint4 = 8 KB
    unsigned short* OutS = (unsigned short*)smem;   // [32][OSTRIDE] aliases W2l

    int t = threadIdx.x;
    int blockRow = blockIdx.x * 32;

    for (int idx = t; idx < 2048; idx += 256) W2l[idx] = w2img[idx];

    // ---- Phase A: spmm (row r = t>>3, lane l = t&7 owns 2 uint4 = 16 feats) ----
    int r = t >> 3, l = t & 7;
    int i = min(blockRow + r, n - 1);
    float di = dinv[i];

    float acc[16];
    {
        uint4 s0 = g16[(size_t)i * 16 + l];
        uint4 s1 = g16[(size_t)i * 16 + 8 + l];
        acc[0] = di * blo(s0.x);  acc[1] = di * bhi(s0.x);
        acc[2] = di * blo(s0.y);  acc[3] = di * bhi(s0.y);
        acc[4] = di * blo(s0.z);  acc[5] = di * bhi(s0.z);
        acc[6] = di * blo(s0.w);  acc[7] = di * bhi(s0.w);
        acc[8] = di * blo(s1.x);  acc[9] = di * bhi(s1.x);
        acc[10] = di * blo(s1.y); acc[11] = di * bhi(s1.y);
        acc[12] = di * blo(s1.z); acc[13] = di * bhi(s1.z);
        acc[14] = di * blo(s1.w); acc[15] = di * bhi(s1.w);
    }
    int e0 = rowptr[i], e1 = rowptr[i + 1];
    int e = e0;
    for (; e + 4 <= e1; e += 4) {
        int s0 = col[e], s1 = col[e + 1], s2 = col[e + 2], s3 = col[e + 3];
        uint4 a0 = g16[(size_t)s0 * 16 + l];
        uint4 a1 = g16[(size_t)s0 * 16 + 8 + l];
        uint4 c0 = g16[(size_t)s1 * 16 + l];
        uint4 c1 = g16[(size_t)s1 * 16 + 8 + l];
        uint4 d0 = g16[(size_t)s2 * 16 + l];
        uint4 d1 = g16[(size_t)s2 * 16 + 8 + l];
        uint4 f0 = g16[(size_t)s3 * 16 + l];
        uint4 f1 = g16[(size_t)s3 * 16 + 8 + l];
        float w0 = dinv[s0], w1 = dinv[s1], w2 = dinv[s2], w3 = dinv[s3];
        acc[0]  = fmaf(w0, blo(a0.x), fmaf(w1, blo(c0.x), fmaf(w2, blo(d0.x), fmaf(w3, blo(f0.x), acc[0]))));
        acc[1]  = fmaf(w0, bhi(a0.x), fmaf(w1, bhi(c0.x), fmaf(w2, bhi(d0.x), fmaf(w3, bhi(f0.x), acc[1]))));
        acc[2]  = fmaf(w0, blo(a0.y), fmaf(w1, blo(c0.y), fmaf(w2, blo(d0.y), fmaf(w3, blo(f0.y), acc[2]))));
        acc[3]  = fmaf(w0, bhi(a0.y), fmaf(w1, bhi(c0.y), fmaf(w2, bhi(d0.y), fmaf(w3, bhi(f0.y), acc[3]))));
        acc[4]  = fmaf(w0, blo(a0.z), fmaf(w1, blo(c0.z), fmaf(w2, blo(d0.z), fmaf(w3, blo(f0.z), acc[4]))));
        acc[5]  = fmaf(w0, bhi(a0.z), fmaf(w1, bhi(c0.z), fmaf(w2, bhi(d0.z), fmaf(w3, bhi(f0.z), acc[5]))));
        acc[6]  = fmaf(w0, blo(a0.w), fmaf(w1, blo(c0.w), fmaf(w2, blo(d0.w), fmaf(w3, blo(f0.w), acc[6]))));
        acc[7]  = fmaf(w0, bhi(a0.w), fmaf(w1, bhi(c0.w), fmaf(w2, bhi(d0.w), fmaf(w3, bhi(f0.w), acc[7]))));
        acc[8]  = fmaf(w0, blo(a1.x), fmaf(w1, blo(c1.x), fmaf(w2, blo(d1.x), fmaf(w3, blo(f1.x), acc[8]))));
        acc[9]  = fmaf(w0, bhi(a1.x), fmaf(w1, bhi(c1.x), fmaf(w2, bhi(d1.x), fmaf(w3, bhi(f1.x), acc[9]))));
        acc[10] = fmaf(w0, blo(a1.y), fmaf(w1, blo(c1.y), fmaf(w2, blo(d1.y), fmaf(w3, blo(f1.y), acc[10]))));
        acc[11] = fmaf(w0, bhi(a1.y), fmaf(w1, bhi(c1.y), fmaf(w2, bhi(d1.y), fmaf(w3, bhi(f1.y), acc[11]))));
        acc[12] = fmaf(w0, blo(a1.z), fmaf(w1, blo(c1.z), fmaf(w2, blo(d1.z), fmaf(w3, blo(f1.z), acc[12]))));
        acc[13] = fmaf(w0, bhi(a1.z), fmaf(w1, bhi(c1.z), fmaf(w2, bhi(d1.z), fmaf(w3, bhi(f1.z), acc[13]))));
        acc[14] = fmaf(w0, blo(a1.w), fmaf(w1, blo(c1.w), fmaf(w2, blo(d1.w), fmaf(w3, blo(f1.w), acc[14]))));
        acc[15] = fmaf(w0, bhi(a1.w), fmaf(w1, bhi(c1.w), fmaf(w2, bhi(d1.w), fmaf(w3, bhi(f1.w), acc[15]))));
    }
    for (; e < e1; e++) {
        int s0 = col[e];
        uint4 a0 = g16[(size_t)s0 * 16 + l];
        uint4 a1 = g16[(size_t)s0 * 16 + 8 + l];
        float w0 = dinv[s0];
        acc[0]  = fmaf(w0, blo(a0.x), acc[0]);  acc[1]  = fmaf(w0, bhi(a0.x), acc[1]);
        acc[2]  = fmaf(w0, blo(a0.y), acc[2]);  acc[3]  = fmaf(w0, bhi(a0.y), acc[3]);
        acc[4]  = fmaf(w0, blo(a0.z), acc[4]);  acc[5]  = fmaf(w0, bhi(a0.z), acc[5]);
        acc[6]  = fmaf(w0, blo(a0.w), acc[6]);  acc[7]  = fmaf(w0, bhi(a0.w), acc[7]);
        acc[8]  = fmaf(w0, blo(a1.x), acc[8]);  acc[9]  = fmaf(w0, bhi(a1.x), acc[9]);
        acc[10] = fmaf(w0, blo(a1.y), acc[10]); acc[11] = fmaf(w0, bhi(a1.y), acc[11]);
        acc[12] = fmaf(w0, blo(a1.z), acc[12]); acc[13] = fmaf(w0, bhi(a1.z), acc[13]);
        acc[14] = fmaf(w0, blo(a1.w), acc[14]); acc[15] = fmaf(w0, bhi(a1.w), acc[15]);
    }

    // h1 = relu(acc*di + b1); pack bf16 -> Hl (kb ^ (row&15) swizzle)
    {
        const float* bp0 = b1 + l * 8;
        const float* bp1 = b1 + 64 + l * 8;
        float4 b00 = *(const float4*)&bp0[0], b01 = *(const float4*)&bp0[4];
        float4 b10 = *(const float4*)&bp1[0], b11 = *(const float4*)&bp1[4];
        float h[16];
        h[0] = fmaxf(fmaf(acc[0], di, b00.x), 0.f);
        h[1] = fmaxf(fmaf(acc[1], di, b00.y), 0.f);
        h[2] = fmaxf(fmaf(acc[2], di, b00.z), 0.f);
        h[3] = fmaxf(fmaf(acc[3], di, b00.w), 0.f);
        h[4] = fmaxf(fmaf(acc[4], di, b01.x), 0.f);
        h[5] = fmaxf(fmaf(acc[5], di, b01.y), 0.f);
        h[6] = fmaxf(fmaf(acc[6], di, b01.z), 0.f);
        h[7] = fmaxf(fmaf(acc[7], di, b01.w), 0.f);
        h[8] = fmaxf(fmaf(acc[8], di, b10.x), 0.f);
        h[9] = fmaxf(fmaf(acc[9], di, b10.y), 0.f);
        h[10] = fmaxf(fmaf(acc[10], di, b10.z), 0.f);
        h[11] = fmaxf(fmaf(acc[11], di, b10.w), 0.f);
        h[12] = fmaxf(fmaf(acc[12], di, b11.x), 0.f);
        h[13] = fmaxf(fmaf(acc[13], di, b11.y), 0.f);
        h[14] = fmaxf(fmaf(acc[14], di, b11.z), 0.f);
        h[15] = fmaxf(fmaf(acc[15], di, b11.w), 0.f);
        uint4 p0, p1;
        p0.x = (unsigned int)f2bf(h[0]) | ((unsigned int)f2bf(h[1]) << 16);
        p0.y = (unsigned int)f2bf(h[2]) | ((unsigned int)f2bf(h[3]) << 16);
        p0.z = (unsigned int)f2bf(h[4]) | ((unsigned int)f2bf(h[5]) << 16);
        p0.w = (unsigned int)f2bf(h[6]) | ((unsigned int)f2bf(h[7]) << 16);
        p1.x = (unsigned int)f2bf(h[8]) | ((unsigned int)f2bf(h[9]) << 16);
        p1.y = (unsigned int)f2bf(h[10]) | ((unsigned int)f2bf(h[11]) << 16);
        p1.z = (unsigned int)f2bf(h[12]) | ((unsigned int)f2bf(h[13]) << 16);
        p1.w = (unsigned int)f2bf(h[14]) | ((unsigned int)f2bf(h[15]) << 16);
        int sw = r & 15;
        Hl[r * 16 + (l ^ sw)] = p0;
        Hl[r * 16 + ((l + 8) ^ sw)] = p1;
    }
    __syncthreads();

    // ---- Phase B: gemm2. 4 waves: rt = wv&1 (row-tile of 16), ch = wv>>1 (col-half)
    int lane = t & 63, wv = t >> 6;
    int rt = wv & 1, ch = wv >> 1;
    bf16x8 Af[4];
    {
        int arow = rt * 16 + (lane & 15);
        int asw = arow & 15;
#pragma unroll
        for (int s = 0; s < 4; s++) {
            int kb = s * 4 + (lane >> 4);
            uint4 u = Hl[arow * 16 + (kb ^ asw)];
            Af[s] = *(bf16x8*)&u;
        }
    }
    f32x4 acc2[4];
#pragma unroll
    for (int ntl = 0; ntl < 4; ntl++) acc2[ntl] = (f32x4)(0.f);
#pragma unroll
    for (int s = 0; s < 4; s++) {
        int kb = s * 4 + (lane >> 4);
#pragma unroll
        for (int ntl = 0; ntl < 4; ntl++) {
            int c = (ch * 4 + ntl) * 16 + (lane & 15);
            bf16x8 bh = *(bf16x8*)&W2l[c * 16 + (kb ^ (lane & 15))];
            acc2[ntl] = MF(Af[s], bh, acc2[ntl]);
        }
    }

    int rl0 = rt * 16 + (lane >> 4) * 4;
    float dr[4];
#pragma unroll
    for (int rr = 0; rr < 4; rr++) dr[rr] = dinv[min(blockRow + rl0 + rr, n - 1)];
    __syncthreads();   // all W2l reads done before OutS aliases it
#pragma unroll
    for (int ntl = 0; ntl < 4; ntl++) {
        int c = (ch * 4 + ntl) * 16 + (lane & 15);
#pragma unroll
        for (int rr = 0; rr < 4; rr++)
            OutS[(rl0 + rr) * OSTRIDE + c] = f2bf(acc2[ntl][rr] * dr[rr]);
    }
    __syncthreads();
    {
        int grow = blockRow + r;
        if (grow < n) {
            uint4 v0 = *(uint4*)&OutS[r * OSTRIDE + l * 16];
            uint4 v1 = *(uint4*)&OutS[r * OSTRIDE + l * 16 + 8];
            *(uint4*)&g2[(size_t)grow * 128 + l * 16] = v0;
            *(uint4*)&g2[(size_t)grow * 128 + l * 16 + 8] = v1;
        }
    }
}

// ------------------------------ SpMM (final layer) --------------------------
// Feature-split halves; unroll 8; NT fp32 stores.
__global__ void spmm_kernel(const uint4* __restrict__ g16, const int* __restrict__ rowptr,
                            const int* __restrict__ col, const float* __restrict__ dinv,
                            const float* __restrict__ bias, float* __restrict__ outv,
                            int n, int nhb) {
    int half = (blockIdx.x >= nhb) ? 1 : 0;
    int rb = blockIdx.x - half * nhb;
    int i = rb * 32 + (threadIdx.x >> 3);
    if (i >= n) return;
    int c = threadIdx.x & 7;

    const uint4* gp = g16 + half * 8 + c;
    float acc[8];
    uint4 sv = gp[(size_t)i * 16];
    acc[0] = blo(sv.x); acc[1] = bhi(sv.x);
    acc[2] = blo(sv.y); acc[3] = bhi(sv.y);
    acc[4] = blo(sv.z); acc[5] = bhi(sv.z);
    acc[6] = blo(sv.w); acc[7] = bhi(sv.w);

    int e0 = rowptr[i], e1 = rowptr[i + 1];
    int e = e0;
    for (; e + 8 <= e1; e += 8) {
        uint4 v0 = gp[(size_t)col[e] * 16];
        uint4 v1 = gp[(size_t)col[e + 1] * 16];
        uint4 v2 = gp[(size_t)col[e + 2] * 16];
        uint4 v3 = gp[(size_t)col[e + 3] * 16];
        uint4 v4 = gp[(size_t)col[e + 4] * 16];
        uint4 v5 = gp[(size_t)col[e + 5] * 16];
        uint4 v6 = gp[(size_t)col[e + 6] * 16];
        uint4 v7 = gp[(size_t)col[e + 7] * 16];
        acc[0] += ((blo(v0.x) + blo(v1.x)) + (blo(v2.x) + blo(v3.x))) +
                  ((blo(v4.x) + blo(v5.x)) + (blo(v6.x) + blo(v7.x)));
        acc[1] += ((bhi(v0.x) + bhi(v1.x)) + (bhi(v2.x) + bhi(v3.x))) +
                  ((bhi(v4.x) + bhi(v5.x)) + (bhi(v6.x) + bhi(v7.x)));
        acc[2] += ((blo(v0.y) + blo(v1.y)) + (blo(v2.y) + blo(v3.y))) +
                  ((blo(v4.y) + blo(v5.y)) + (blo(v6.y) + blo(v7.y)));
        acc[3] += ((bhi(v0.y) + bhi(v1.y)) + (bhi(v2.y) + bhi(v3.y))) +
                  ((bhi(v4.y) + bhi(v5.y)) + (bhi(v6.y) + bhi(v7.y)));
        acc[4] += ((blo(v0.z) + blo(v1.z)) + (blo(v2.z) + blo(v3.z))) +
                  ((blo(v4.z) + blo(v5.z)) + (blo(v6.z) + blo(v7.z)));
        acc[5] += ((bhi(v0.z) + bhi(v1.z)) + (bhi(v2.z) + bhi(v3.z))) +
                  ((bhi(v4.z) + bhi(v5.z)) + (bhi(v6.z) + bhi(v7.z)));
        acc[6] += ((blo(v0.w) + blo(v1.w)) + (blo(v2.w) + blo(v3.w))) +
                  ((blo(v4.w) + blo(v5.w)) + (blo(v6.w) + blo(v7.w)));
        acc[7] += ((bhi(v0.w) + bhi(v1.w)) + (bhi(v2.w) + bhi(v3.w))) +
                  ((bhi(v4.w) + bhi(v5.w)) + (bhi(v6.w) + bhi(v7.w)));
    }
    for (; e + 2 <= e1; e += 2) {
        uint4 v0 = gp[(size_t)col[e] * 16];
        uint4 v1 = gp[(size_t)col[e + 1] * 16];
        acc[0] += blo(v0.x) + blo(v1.x); acc[1] += bhi(v0.x) + bhi(v1.x);
        acc[2] += blo(v0.y) + blo(v1.y); acc[3] += bhi(v0.y) + bhi(v1.y);
        acc[4] += blo(v0.z) + blo(v1.z); acc[5] += bhi(v0.z) + bhi(v1.z);
        acc[6] += blo(v0.w) + blo(v1.w); acc[7] += bhi(v0.w) + bhi(v1.w);
    }
    if (e < e1) {
        uint4 v0 = gp[(size_t)col[e] * 16];
        acc[0] += blo(v0.x); acc[1] += bhi(v0.x);
        acc[2] += blo(v0.y); acc[3] += bhi(v0.y);
        acc[4] += blo(v0.z); acc[5] += bhi(v0.z);
        acc[6] += blo(v0.w); acc[7] += bhi(v0.w);
    }

    float di = dinv[i];
    const float4* b4 = (const float4*)(bias + half * 64);
    float4 bv0 = b4[c * 2], bv1 = b4[c * 2 + 1];
    float r0[8];
    r0[0] = fmaf(acc[0], di, bv0.x);
    r0[1] = fmaf(acc[1], di, bv0.y);
    r0[2] = fmaf(acc[2], di, bv0.z);
    r0[3] = fmaf(acc[3], di, bv0.w);
    r0[4] = fmaf(acc[4], di, bv1.x);
    r0[5] = fmaf(acc[5], di, bv1.y);
    r0[6] = fmaf(acc[6], di, bv1.z);
    r0[7] = fmaf(acc[7], di, bv1.w);
    float* o = outv + (size_t)i * 128 + half * 64 + c * 8;
    f32x4 a = *(f32x4*)&r0[0];
    f32x4 b = *(f32x4*)&r0[4];
    __builtin_nontemporal_store(a, (f32x4*)o);
    __builtin_nontemporal_store(b, (f32x4*)(o + 4));
}

extern "C" void kernel_launch(void* const* d_in, const int* in_sizes, int n_in,
                              void* d_out, int out_size, void* d_ws, size_t ws_size,
                              hipStream_t stream) {
    const float* x      = (const float*)d_in[0];
    const int*   ei     = (const int*)d_in[1];
    const float* gate_W = (const float*)d_in[2];
    const float* gate_b = (const float*)d_in[3];
    const float* W1     = (const float*)d_in[4];
    const float* b1     = (const float*)d_in[5];
    const float* W2     = (const float*)d_in[6];
    const float* b2     = (const float*)d_in[7];
    float* out = (float*)d_out;

    const int N = in_sizes[0] / 128;
    const int E = in_sizes[1] / 2;
    const int* src = ei;
    const int* dst = ei + E;
    const int NB = (N + BUCKET_W - 1) / BUCKET_W;

    char* p = (char*)d_ws;
    auto alloc = [&](size_t bytes) { char* q = p; p += (bytes + 255) & ~(size_t)255; return q; };
    int*   rowptr  = (int*)alloc(((size_t)N + 1) * 4);
    float* dinv    = (float*)alloc((size_t)N * 4);
    int*   colb    = (int*)alloc((size_t)E * 4);
    int*   bcursor = (int*)alloc((size_t)NB * 4);
    int*   bbase   = (int*)alloc(((size_t)NB + 1) * 4);
    uint4* wimg    = (uint4*)alloc((size_t)3 * 2048 * 16);
    unsigned int*   part   = (unsigned int*)alloc((size_t)NB * CAP * 4);
    unsigned short* hpack  = (unsigned short*)alloc((size_t)N * 128 * 2);
    unsigned short* g16    = (unsigned short*)alloc((size_t)N * 128 * 2);
    unsigned short* g2buf  = (unsigned short*)alloc((size_t)N * 128 * 2);

    const int pblocks = 256;
    const int chunk = (E + pblocks - 1) / pblocks;
    int gblocks = (N + 127) / 128;
    int fblocks = (N + 31) / 32;
    int nhb = (N + 31) / 32;

    prepinit_kernel<<<13, 512, 0, stream>>>(gate_W, W1, W2, wimg, bcursor, NB);
    pg_kernel<<<256 + gblocks, 512, 0, stream>>>(src, dst, bcursor, part, E, NB, chunk,
                                                 x, wimg, gate_b, hpack, N);
    bucket_scan_kernel<<<1, 512, 0, stream>>>(bcursor, bbase, NB);
    fg_kernel<<<NB + gblocks, 512, 0, stream>>>(part, bbase, rowptr, dinv, colb, N, NB,
                                                hpack, wimg + 2048, g16);
    spmm_gemm_kernel<<<fblocks, 256, 0, stream>>>((const uint4*)g16, rowptr, colb,
                                                  dinv, b1, wimg + 4096, g2buf, N);
    spmm_kernel<<<2 * nhb, 256, 0, stream>>>((const uint4*)g2buf, rowptr, colb,
                                             dinv, b2, out, N, nhb);
}

// Round 13
// 208.939 us; speedup vs baseline: 1.5313x; 1.0020x over previous
//
#include <hip/hip_runtime.h>
#include <hip/hip_bf16.h>
#include <math.h>

// ---------------------------------------------------------------------------
// GCNEncoderWithGate R13 (= R12 with spmm_gemm occupancy fix):
//  - spmm_gemm: W2 LDS staging removed; MFMA B-frags read directly from the
//    L2-resident weight image. LDS 40960 -> 16896 (Hl 8K + OutS 8.7K)
//    -> 8 blocks/CU (wave-capped) during the latency-bound gather phase.
//  - everything else identical to R12.
// ---------------------------------------------------------------------------

#define BUCKET_SHIFT 8
#define BUCKET_W 256
#define CAP 4864
#define NB_MAX 512
#define OSTRIDE 136

typedef __attribute__((ext_vector_type(8))) short bf16x8;
typedef __attribute__((ext_vector_type(4))) float f32x4;

__device__ __forceinline__ unsigned short f2bf(float x) {
    unsigned int u = __float_as_uint(x);
    unsigned int r = (u + 0x7FFFu + ((u >> 16) & 1u)) >> 16;   // RNE
    return (unsigned short)r;
}
__device__ __forceinline__ float blo(unsigned int u) { return __uint_as_float(u << 16); }
__device__ __forceinline__ float bhi(unsigned int u) { return __uint_as_float(u & 0xFFFF0000u); }

__device__ __forceinline__ void cvt_hilo8(const float* v, bf16x8& hi, bf16x8& lo) {
#pragma unroll
    for (int j = 0; j < 8; j++) {
        unsigned short h = f2bf(v[j]);
        float hf = __uint_as_float((unsigned int)h << 16);
        hi[j] = (short)h;
        lo[j] = (short)f2bf(v[j] - hf);
    }
}

__device__ __forceinline__ f32x4 MF(bf16x8 a, bf16x8 b, f32x4 c) {
    return __builtin_amdgcn_mfma_f32_16x16x32_bf16(a, b, c, 0, 0, 0);
}

// ---------------------- prep weights + cursor init (1 dispatch) -------------
__global__ __launch_bounds__(512)
void prepinit_kernel(const float* __restrict__ W0, const float* __restrict__ W1,
                     const float* __restrict__ W2, uint4* __restrict__ img,
                     int* __restrict__ bcursor, int NB) {
    int b = blockIdx.x, t = threadIdx.x;
    if (b < 12) {
        int idx = b * 512 + t;            // 0..6143 = 3*2048
        int c = idx & 127, kb = (idx >> 7) & 15, w = idx >> 11;
        const float* W = (w == 0) ? W0 : (w == 1) ? W1 : W2;
        bf16x8 hb;
#pragma unroll
        for (int j = 0; j < 8; j++) hb[j] = (short)f2bf(W[(size_t)(kb * 8 + j) * 128 + c]);
        img[w * 2048 + c * 16 + (kb ^ (c & 15))] = *(uint4*)&hb;
    } else {
        if (t < NB) bcursor[t] = 0;
    }
}

// ---------------------- partition ∪ gate (1 dispatch) -----------------------
__device__ __forceinline__ void partition_body(char* smem, int b, int t,
                                               const int* __restrict__ src,
                                               const int* __restrict__ dst,
                                               int* __restrict__ bucketCursor,
                                               unsigned int* __restrict__ part,
                                               int E, int NB, int chunk) {
    int* hist  = (int*)smem;
    int* basec = hist + NB_MAX;
    int e0 = b * chunk;
    int e1 = min(E, e0 + chunk);

    for (int i = t; i < NB; i += 512) hist[i] = 0;
    __syncthreads();
    for (int e = e0 + t; e < e1; e += 512) {
        int bb = dst[e] >> BUCKET_SHIFT;
        atomicAdd(&hist[bb], 1);
    }
    __syncthreads();
    for (int i = t; i < NB; i += 512) {
        int c = hist[i];
        basec[i] = c ? atomicAdd(&bucketCursor[i], c) : 0;
    }
    __syncthreads();
    for (int i = t; i < NB; i += 512) hist[i] = 0;
    __syncthreads();
    for (int e = e0 + t; e < e1; e += 512) {
        int d = dst[e], s = src[e];
        int bb = d >> BUCKET_SHIFT;
        int r = atomicAdd(&hist[bb], 1);
        int pos = basec[bb] + r;
        if (pos < CAP)
            part[(size_t)bb * CAP + pos] = ((unsigned int)(d & (BUCKET_W - 1)) << 17) | (unsigned int)s;
    }
}

__device__ __forceinline__ void gate_body(char* smem, int gb, int t,
                                          const float* __restrict__ x,
                                          const uint4* __restrict__ gimg,
                                          const float* __restrict__ gate_b,
                                          unsigned short* __restrict__ hpack, int n) {
    uint4* Wl = (uint4*)smem;
    unsigned short* OutS = (unsigned short*)(smem + 32768);
    int lane = t & 63, wv = t >> 6;
    int blockRow = gb * 128;

    for (int idx = t; idx < 2048; idx += 512) Wl[idx] = gimg[idx];

    bf16x8 Ahi[4], Alo[4];
    {
        int arow = blockRow + wv * 16 + (lane & 15);
        const float* ap = x + (size_t)min(arow, n - 1) * 128 + (lane >> 4) * 8;
#pragma unroll
        for (int s = 0; s < 4; s++) {
            float v[8];
            *(float4*)&v[0] = *(const float4*)&ap[s * 32];
            *(float4*)&v[4] = *(const float4*)&ap[s * 32 + 4];
            cvt_hilo8(v, Ahi[s], Alo[s]);
        }
    }
    __syncthreads();

    f32x4 acc[8];
#pragma unroll
    for (int nt = 0; nt < 8; nt++) acc[nt] = (f32x4)(0.f);
#pragma unroll
    for (int s = 0; s < 4; s++) {
        int kb = s * 4 + (lane >> 4);
#pragma unroll
        for (int nt = 0; nt < 8; nt++) {
            int c = nt * 16 + (lane & 15);
            bf16x8 bh = *(bf16x8*)&Wl[c * 16 + (kb ^ (lane & 15))];
            acc[nt] = MF(Ahi[s], bh, acc[nt]);
            acc[nt] = MF(Alo[s], bh, acc[nt]);
        }
    }

    int rl0 = wv * 16 + (lane >> 4) * 4;
#pragma unroll
    for (int nt = 0; nt < 8; nt++) {
        int c = nt * 16 + (lane & 15);
        float gb2 = gate_b[c];
#pragma unroll
        for (int r = 0; r < 4; r++) {
            int grow = min(blockRow + rl0 + r, n - 1);
            float xv = x[(size_t)grow * 128 + c];
            float hv = xv / (1.f + __expf(-(acc[nt][r] + gb2)));
            OutS[(rl0 + r) * OSTRIDE + c] = f2bf(hv);
        }
    }
    __syncthreads();
    {
        int row = t >> 2;
        int c0 = (t & 3) * 32;
        int grow = blockRow + row;
        if (grow < n) {
#pragma unroll
            for (int j = 0; j < 4; j++) {
                uint4 v = *(uint4*)&OutS[row * OSTRIDE + c0 + j * 8];
                *(uint4*)&hpack[(size_t)grow * 128 + c0 + j * 8] = v;
            }
        }
    }
}

__global__ __launch_bounds__(512)
void pg_kernel(const int* __restrict__ src, const int* __restrict__ dst,
               int* __restrict__ bucketCursor, unsigned int* __restrict__ part,
               int E, int NB, int chunk,
               const float* __restrict__ x, const uint4* __restrict__ gimg,
               const float* __restrict__ gate_b, unsigned short* __restrict__ hpack, int n) {
    __shared__ __align__(16) char smem[67584];
    int b = blockIdx.x, t = threadIdx.x;
    if (b < 256) partition_body(smem, b, t, src, dst, bucketCursor, part, E, NB, chunk);
    else         gate_body(smem, b - 256, t, x, gimg, gate_b, hpack, n);
}

// ------------------------------ bucket scan --------------------------------
__global__ __launch_bounds__(512)
void bucket_scan_kernel(const int* __restrict__ bucketCursor,
                        int* __restrict__ bucketBase, int NB) {
    __shared__ int sm[NB_MAX];
    int t = threadIdx.x;
    int v = (t < NB) ? min(bucketCursor[t], CAP) : 0;
    sm[t] = v;
    __syncthreads();
    for (int off = 1; off < NB_MAX; off <<= 1) {
        int a = (t >= off) ? sm[t - off] : 0;
        __syncthreads();
        sm[t] += a;
        __syncthreads();
    }
    if (t < NB) bucketBase[t + 1] = sm[t];
    if (t == 0) bucketBase[0] = 0;
}

// ---------------------- bucket_fill ∪ gemm1 (1 dispatch) --------------------
__device__ __forceinline__ void fill_body(char* smem, int b, int t,
                                          const unsigned int* __restrict__ part,
                                          const int* __restrict__ bucketBase,
                                          int* __restrict__ rowptr, float* __restrict__ dinv,
                                          int* __restrict__ col, int N, int NB) {
    unsigned int* eLDS = (unsigned int*)smem;
    int* deg  = (int*)(smem + CAP * 4);
    int* cur  = deg + BUCKET_W;
    int* wsum = cur + BUCKET_W;   // 8 ints

    int base = bucketBase[b];
    int cnt = bucketBase[b + 1] - base;

    for (int i = t; i < cnt; i += 512) eLDS[i] = part[(size_t)b * CAP + i];
    if (t < 256) deg[t] = 0;
    __syncthreads();
    for (int i = t; i < cnt; i += 512) atomicAdd(&deg[eLDS[i] >> 17], 1);
    __syncthreads();

    int v = (t < 256) ? deg[t] : 0;
    int incl = v;
    int lane = t & 63, w = t >> 6;
    for (int off = 1; off < 64; off <<= 1) {
        int u = __shfl_up(incl, off, 64);
        if (lane >= off) incl += u;
    }
    if (lane == 63) wsum[w] = incl;
    __syncthreads();
    int add = 0;
#pragma unroll
    for (int j = 0; j < 4; j++) if (j < w) add += wsum[j];
    int excl = add + incl - v;
    if (t < 256) {
        cur[t] = excl;
        int gnode = b * BUCKET_W + t;
        if (gnode < N) {
            rowptr[gnode] = base + excl;
            dinv[gnode] = rsqrtf((float)(v + 1));
        }
    }
    if (b == NB - 1 && t == 0) rowptr[N] = base + cnt;
    __syncthreads();

    for (int i = t; i < cnt; i += 512) {
        unsigned int ev = eLDS[i];
        int dl = ev >> 17;
        int p = atomicAdd(&cur[dl], 1);
        col[base + p] = (int)(ev & 0x1FFFFu);
    }
}

// gemm1 (SCALE=0): G1 = A@W1 unscaled -> fusable with fill (no dinv read)
__device__ __forceinline__ void gemm_body(char* smem, int gb, int t,
                                          const unsigned short* __restrict__ A,
                                          const uint4* __restrict__ wimg,
                                          unsigned short* __restrict__ g, int n) {
    uint4* Wl = (uint4*)smem;
    unsigned short* OutS = (unsigned short*)(smem + 32768);
    int lane = t & 63, wv = t >> 6;
    int blockRow = gb * 128;

    for (int idx = t; idx < 2048; idx += 512) Wl[idx] = wimg[idx];

    bf16x8 Af[4];
    {
        int arow = blockRow + wv * 16 + (lane & 15);
        const uint4* ap = (const uint4*)(A + (size_t)min(arow, n - 1) * 128);
#pragma unroll
        for (int s = 0; s < 4; s++) {
            uint4 u = ap[(lane >> 4) + s * 4];
            Af[s] = *(bf16x8*)&u;
        }
    }
    __syncthreads();

    f32x4 acc[8];
#pragma unroll
    for (int nt = 0; nt < 8; nt++) acc[nt] = (f32x4)(0.f);
#pragma unroll
    for (int s = 0; s < 4; s++) {
        int kb = s * 4 + (lane >> 4);
#pragma unroll
        for (int nt = 0; nt < 8; nt++) {
            int c = nt * 16 + (lane & 15);
            bf16x8 bh = *(bf16x8*)&Wl[c * 16 + (kb ^ (lane & 15))];
            acc[nt] = MF(Af[s], bh, acc[nt]);
        }
    }

    int rl0 = wv * 16 + (lane >> 4) * 4;
#pragma unroll
    for (int nt = 0; nt < 8; nt++) {
        int c = nt * 16 + (lane & 15);
#pragma unroll
        for (int r = 0; r < 4; r++)
            OutS[(rl0 + r) * OSTRIDE + c] = f2bf(acc[nt][r]);
    }
    __syncthreads();
    {
        int row = t >> 2;
        int c0 = (t & 3) * 32;
        int grow = blockRow + row;
        if (grow < n) {
#pragma unroll
            for (int j = 0; j < 4; j++) {
                uint4 v = *(uint4*)&OutS[row * OSTRIDE + c0 + j * 8];
                *(uint4*)&g[(size_t)grow * 128 + c0 + j * 8] = v;
            }
        }
    }
}

__global__ __launch_bounds__(512)
void fg_kernel(const unsigned int* __restrict__ part, const int* __restrict__ bucketBase,
               int* __restrict__ rowptr, float* __restrict__ dinv, int* __restrict__ col,
               int N, int NB,
               const unsigned short* __restrict__ A, const uint4* __restrict__ wimg,
               unsigned short* __restrict__ g) {
    __shared__ __align__(16) char smem[67584];
    int b = blockIdx.x, t = threadIdx.x;
    if (b < NB) fill_body(smem, b, t, part, bucketBase, rowptr, dinv, col, N, NB);
    else        gemm_body(smem, b - NB, t, A, wimg, g, N);
}

// ------------------- fused spmm1 + gemm2 (1 dispatch) -----------------------
// 32 rows/block, 256 thr, LDS 16896 = Hl 8K + OutS 8.7K -> 8 blocks/CU.
// Phase A: h1 = relu(di*(sum dinv[s]*G1[s] + di*G1[i]) + b1)  (unroll 4)
// Phase B: g2 = (h1 @ W2) * di via MFMA; B-frags read DIRECTLY from the
// L2-resident weight image (no LDS staging -> occupancy for the gather).
__global__ __launch_bounds__(256)
void spmm_gemm_kernel(const uint4* __restrict__ g16, const int* __restrict__ rowptr,
                      const int* __restrict__ col, const float* __restrict__ dinv,
                      const float* __restrict__ b1, const uint4* __restrict__ w2img,
                      unsigned short* __restrict__ g2, int n) {
    __shared__ __align__(16) char smem[16896];
    uint4* Hl = (uint4*)smem;                           // 32 rows x 16 uint4 = 8 KB
    unsigned short* OutS = (unsigned short*)(smem + 8192);  // [32][OSTRIDE] = 8.7 KB

    int t = threadIdx.x;
    int blockRow = blockIdx.x * 32;

    // ---- Phase A: spmm (row r = t>>3, lane l = t&7 owns 2 uint4 = 16 feats) ----
    int r = t >> 3, l = t & 7;
    int i = min(blockRow + r, n - 1);
    float di = dinv[i];

    float acc[16];
    {
        uint4 s0 = g16[(size_t)i * 16 + l];
        uint4 s1 = g16[(size_t)i * 16 + 8 + l];
        acc[0] = di * blo(s0.x);  acc[1] = di * bhi(s0.x);
        acc[2] = di * blo(s0.y);  acc[3] = di * bhi(s0.y);
        acc[4] = di * blo(s0.z);  acc[5] = di * bhi(s0.z);
        acc[6] = di * blo(s0.w);  acc[7] = di * bhi(s0.w);
        acc[8] = di * blo(s1.x);  acc[9] = di * bhi(s1.x);
        acc[10] = di * blo(s1.y); acc[11] = di * bhi(s1.y);
        acc[12] = di * blo(s1.z); acc[13] = di * bhi(s1.z);
        acc[14] = di * blo(s1.w); acc[15] = di * bhi(s1.w);
    }
    int e0 = rowptr[i], e1 = rowptr[i + 1];
    int e = e0;
    for (; e + 4 <= e1; e += 4) {
        int s0 = col[e], s1 = col[e + 1], s2 = col[e + 2], s3 = col[e + 3];
        uint4 a0 = g16[(size_t)s0 * 16 + l];
        uint4 a1 = g16[(size_t)s0 * 16 + 8 + l];
        uint4 c0 = g16[(size_t)s1 * 16 + l];
        uint4 c1 = g16[(size_t)s1 * 16 + 8 + l];
        uint4 d0 = g16[(size_t)s2 * 16 + l];
        uint4 d1 = g16[(size_t)s2 * 16 + 8 + l];
        uint4 f0 = g16[(size_t)s3 * 16 + l];
        uint4 f1 = g16[(size_t)s3 * 16 + 8 + l];
        float w0 = dinv[s0], w1 = dinv[s1], w2 = dinv[s2], w3 = dinv[s3];
        acc[0]  = fmaf(w0, blo(a0.x), fmaf(w1, blo(c0.x), fmaf(w2, blo(d0.x), fmaf(w3, blo(f0.x), acc[0]))));
        acc[1]  = fmaf(w0, bhi(a0.x), fmaf(w1, bhi(c0.x), fmaf(w2, bhi(d0.x), fmaf(w3, bhi(f0.x), acc[1]))));
        acc[2]  = fmaf(w0, blo(a0.y), fmaf(w1, blo(c0.y), fmaf(w2, blo(d0.y), fmaf(w3, blo(f0.y), acc[2]))));
        acc[3]  = fmaf(w0, bhi(a0.y), fmaf(w1, bhi(c0.y), fmaf(w2, bhi(d0.y), fmaf(w3, bhi(f0.y), acc[3]))));
        acc[4]  = fmaf(w0, blo(a0.z), fmaf(w1, blo(c0.z), fmaf(w2, blo(d0.z), fmaf(w3, blo(f0.z), acc[4]))));
        acc[5]  = fmaf(w0, bhi(a0.z), fmaf(w1, bhi(c0.z), fmaf(w2, bhi(d0.z), fmaf(w3, bhi(f0.z), acc[5]))));
        acc[6]  = fmaf(w0, blo(a0.w), fmaf(w1, blo(c0.w), fmaf(w2, blo(d0.w), fmaf(w3, blo(f0.w), acc[6]))));
        acc[7]  = fmaf(w0, bhi(a0.w), fmaf(w1, bhi(c0.w), fmaf(w2, bhi(d0.w), fmaf(w3, bhi(f0.w), acc[7]))));
        acc[8]  = fmaf(w0, blo(a1.x), fmaf(w1, blo(c1.x), fmaf(w2, blo(d1.x), fmaf(w3, blo(f1.x), acc[8]))));
        acc[9]  = fmaf(w0, bhi(a1.x), fmaf(w1, bhi(c1.x), fmaf(w2, bhi(d1.x), fmaf(w3, bhi(f1.x), acc[9]))));
        acc[10] = fmaf(w0, blo(a1.y), fmaf(w1, blo(c1.y), fmaf(w2, blo(d1.y), fmaf(w3, blo(f1.y), acc[10]))));
        acc[11] = fmaf(w0, bhi(a1.y), fmaf(w1, bhi(c1.y), fmaf(w2, bhi(d1.y), fmaf(w3, bhi(f1.y), acc[11]))));
        acc[12] = fmaf(w0, blo(a1.z), fmaf(w1, blo(c1.z), fmaf(w2, blo(d1.z), fmaf(w3, blo(f1.z), acc[12]))));
        acc[13] = fmaf(w0, bhi(a1.z), fmaf(w1, bhi(c1.z), fmaf(w2, bhi(d1.z), fmaf(w3, bhi(f1.z), acc[13]))));
        acc[14] = fmaf(w0, blo(a1.w), fmaf(w1, blo(c1.w), fmaf(w2, blo(d1.w), fmaf(w3, blo(f1.w), acc[14]))));
        acc[15] = fmaf(w0, bhi(a1.w), fmaf(w1, bhi(c1.w), fmaf(w2, bhi(d1.w), fmaf(w3, bhi(f1.w), acc[15]))));
    }
    for (; e < e1; e++) {
        int s0 = col[e];
        uint4 a0 = g16[(size_t)s0 * 16 + l];
        uint4 a1 = g16[(size_t)s0 * 16 + 8 + l];
        float w0 = dinv[s0];
        acc[0]  = fmaf(w0, blo(a0.x), acc[0]);  acc[1]  = fmaf(w0, bhi(a0.x), acc[1]);
        acc[2]  = fmaf(w0, blo(a0.y), acc[2]);  acc[3]  = fmaf(w0, bhi(a0.y), acc[3]);
        acc[4]  = fmaf(w0, blo(a0.z), acc[4]);  acc[5]  = fmaf(w0, bhi(a0.z), acc[5]);
        acc[6]  = fmaf(w0, blo(a0.w), acc[6]);  acc[7]  = fmaf(w0, bhi(a0.w), acc[7]);
        acc[8]  = fmaf(w0, blo(a1.x), acc[8]);  acc[9]  = fmaf(w0, bhi(a1.x), acc[9]);
        acc[10] = fmaf(w0, blo(a1.y), acc[10]); acc[11] = fmaf(w0, bhi(a1.y), acc[11]);
        acc[12] = fmaf(w0, blo(a1.z), acc[12]); acc[13] = fmaf(w0, bhi(a1.z), acc[13]);
        acc[14] = fmaf(w0, blo(a1.w), acc[14]); acc[15] = fmaf(w0, bhi(a1.w), acc[15]);
    }

    // h1 = relu(acc*di + b1); pack bf16 -> Hl (kb ^ (row&15) swizzle)
    {
        const float* bp0 = b1 + l * 8;
        const float* bp1 = b1 + 64 + l * 8;
        float4 b00 = *(const float4*)&bp0[0], b01 = *(const float4*)&bp0[4];
        float4 b10 = *(const float4*)&bp1[0], b11 = *(const float4*)&bp1[4];
        float h[16];
        h[0] = fmaxf(fmaf(acc[0], di, b00.x), 0.f);
        h[1] = fmaxf(fmaf(acc[1], di, b00.y), 0.f);
        h[2] = fmaxf(fmaf(acc[2], di, b00.z), 0.f);
        h[3] = fmaxf(fmaf(acc[3], di, b00.w), 0.f);
        h[4] = fmaxf(fmaf(acc[4], di, b01.x), 0.f);
        h[5] = fmaxf(fmaf(acc[5], di, b01.y), 0.f);
        h[6] = fmaxf(fmaf(acc[6], di, b01.z), 0.f);
        h[7] = fmaxf(fmaf(acc[7], di, b01.w), 0.f);
        h[8] = fmaxf(fmaf(acc[8], di, b10.x), 0.f);
        h[9] = fmaxf(fmaf(acc[9], di, b10.y), 0.f);
        h[10] = fmaxf(fmaf(acc[10], di, b10.z), 0.f);
        h[11] = fmaxf(fmaf(acc[11], di, b10.w), 0.f);
        h[12] = fmaxf(fmaf(acc[12], di, b11.x), 0.f);
        h[13] = fmaxf(fmaf(acc[13], di, b11.y), 0.f);
        h[14] = fmaxf(fmaf(acc[14], di, b11.z), 0.f);
        h[15] = fmaxf(fmaf(acc[15], di, b11.w), 0.f);
        uint4 p0, p1;
        p0.x = (unsigned int)f2bf(h[0]) | ((unsigned int)f2bf(h[1]) << 16);
        p0.y = (unsigned int)f2bf(h[2]) | ((unsigned int)f2bf(h[3]) << 16);
        p0.z = (unsigned int)f2bf(h[4]) | ((unsigned int)f2bf(h[5]) << 16);
        p0.w = (unsigned int)f2bf(h[6]) | ((unsigned int)f2bf(h[7]) << 16);
        p1.x = (unsigned int)f2bf(h[8]) | ((unsigned int)f2bf(h[9]) << 16);
        p1.y = (unsigned int)f2bf(h[10]) | ((unsigned int)f2bf(h[11]) << 16);
        p1.z = (unsigned int)f2bf(h[12]) | ((unsigned int)f2bf(h[13]) << 16);
        p1.w = (unsigned int)f2bf(h[14]) | ((unsigned int)f2bf(h[15]) << 16);
        int sw = r & 15;
        Hl[r * 16 + (l ^ sw)] = p0;
        Hl[r * 16 + ((l + 8) ^ sw)] = p1;
    }
    __syncthreads();

    // ---- Phase B: gemm2. 4 waves: rt = wv&1 (row-tile of 16), ch = wv>>1 (col-half)
    // B-frags from the L2-resident image (no LDS staging).
    int lane = t & 63, wv = t >> 6;
    int rt = wv & 1, ch = wv >> 1;
    bf16x8 Af[4];
    {
        int arow = rt * 16 + (lane & 15);
        int asw = arow & 15;
#pragma unroll
        for (int s = 0; s < 4; s++) {
            int kb = s * 4 + (lane >> 4);
            uint4 u = Hl[arow * 16 + (kb ^ asw)];
            Af[s] = *(bf16x8*)&u;
        }
    }
    f32x4 acc2[4];
#pragma unroll
    for (int ntl = 0; ntl < 4; ntl++) acc2[ntl] = (f32x4)(0.f);
#pragma unroll
    for (int s = 0; s < 4; s++) {
        int kb = s * 4 + (lane >> 4);
#pragma unroll
        for (int ntl = 0; ntl < 4; ntl++) {
            int c = (ch * 4 + ntl) * 16 + (lane & 15);
            uint4 u = w2img[c * 16 + (kb ^ (lane & 15))];
            acc2[ntl] = MF(Af[s], *(bf16x8*)&u, acc2[ntl]);
        }
    }

    int rl0 = rt * 16 + (lane >> 4) * 4;
    float dr[4];
#pragma unroll
    for (int rr = 0; rr < 4; rr++) dr[rr] = dinv[min(blockRow + rl0 + rr, n - 1)];
#pragma unroll
    for (int ntl = 0; ntl < 4; ntl++) {
        int c = (ch * 4 + ntl) * 16 + (lane & 15);
#pragma unroll
        for (int rr = 0; rr < 4; rr++)
            OutS[(rl0 + rr) * OSTRIDE + c] = f2bf(acc2[ntl][rr] * dr[rr]);
    }
    __syncthreads();
    {
        int grow = blockRow + r;
        if (grow < n) {
            uint4 v0 = *(uint4*)&OutS[r * OSTRIDE + l * 16];
            uint4 v1 = *(uint4*)&OutS[r * OSTRIDE + l * 16 + 8];
            *(uint4*)&g2[(size_t)grow * 128 + l * 16] = v0;
            *(uint4*)&g2[(size_t)grow * 128 + l * 16 + 8] = v1;
        }
    }
}

// ------------------------------ SpMM (final layer) --------------------------
// Feature-split halves; unroll 8; NT fp32 stores.
__global__ void spmm_kernel(const uint4* __restrict__ g16, const int* __restrict__ rowptr,
                            const int* __restrict__ col, const float* __restrict__ dinv,
                            const float* __restrict__ bias, float* __restrict__ outv,
                            int n, int nhb) {
    int half = (blockIdx.x >= nhb) ? 1 : 0;
    int rb = blockIdx.x - half * nhb;
    int i = rb * 32 + (threadIdx.x >> 3);
    if (i >= n) return;
    int c = threadIdx.x & 7;

    const uint4* gp = g16 + half * 8 + c;
    float acc[8];
    uint4 sv = gp[(size_t)i * 16];
    acc[0] = blo(sv.x); acc[1] = bhi(sv.x);
    acc[2] = blo(sv.y); acc[3] = bhi(sv.y);
    acc[4] = blo(sv.z); acc[5] = bhi(sv.z);
    acc[6] = blo(sv.w); acc[7] = bhi(sv.w);

    int e0 = rowptr[i], e1 = rowptr[i + 1];
    int e = e0;
    for (; e + 8 <= e1; e += 8) {
        uint4 v0 = gp[(size_t)col[e] * 16];
        uint4 v1 = gp[(size_t)col[e + 1] * 16];
        uint4 v2 = gp[(size_t)col[e + 2] * 16];
        uint4 v3 = gp[(size_t)col[e + 3] * 16];
        uint4 v4 = gp[(size_t)col[e + 4] * 16];
        uint4 v5 = gp[(size_t)col[e + 5] * 16];
        uint4 v6 = gp[(size_t)col[e + 6] * 16];
        uint4 v7 = gp[(size_t)col[e + 7] * 16];
        acc[0] += ((blo(v0.x) + blo(v1.x)) + (blo(v2.x) + blo(v3.x))) +
                  ((blo(v4.x) + blo(v5.x)) + (blo(v6.x) + blo(v7.x)));
        acc[1] += ((bhi(v0.x) + bhi(v1.x)) + (bhi(v2.x) + bhi(v3.x))) +
                  ((bhi(v4.x) + bhi(v5.x)) + (bhi(v6.x) + bhi(v7.x)));
        acc[2] += ((blo(v0.y) + blo(v1.y)) + (blo(v2.y) + blo(v3.y))) +
                  ((blo(v4.y) + blo(v5.y)) + (blo(v6.y) + blo(v7.y)));
        acc[3] += ((bhi(v0.y) + bhi(v1.y)) + (bhi(v2.y) + bhi(v3.y))) +
                  ((bhi(v4.y) + bhi(v5.y)) + (bhi(v6.y) + bhi(v7.y)));
        acc[4] += ((blo(v0.z) + blo(v1.z)) + (blo(v2.z) + blo(v3.z))) +
                  ((blo(v4.z) + blo(v5.z)) + (blo(v6.z) + blo(v7.z)));
        acc[5] += ((bhi(v0.z) + bhi(v1.z)) + (bhi(v2.z) + bhi(v3.z))) +
                  ((bhi(v4.z) + bhi(v5.z)) + (bhi(v6.z) + bhi(v7.z)));
        acc[6] += ((blo(v0.w) + blo(v1.w)) + (blo(v2.w) + blo(v3.w))) +
                  ((blo(v4.w) + blo(v5.w)) + (blo(v6.w) + blo(v7.w)));
        acc[7] += ((bhi(v0.w) + bhi(v1.w)) + (bhi(v2.w) + bhi(v3.w))) +
                  ((bhi(v4.w) + bhi(v5.w)) + (bhi(v6.w) + bhi(v7.w)));
    }
    for (; e + 2 <= e1; e += 2) {
        uint4 v0 = gp[(size_t)col[e] * 16];
        uint4 v1 = gp[(size_t)col[e + 1] * 16];
        acc[0] += blo(v0.x) + blo(v1.x); acc[1] += bhi(v0.x) + bhi(v1.x);
        acc[2] += blo(v0.y) + blo(v1.y); acc[3] += bhi(v0.y) + bhi(v1.y);
        acc[4] += blo(v0.z) + blo(v1.z); acc[5] += bhi(v0.z) + bhi(v1.z);
        acc[6] += blo(v0.w) + blo(v1.w); acc[7] += bhi(v0.w) + bhi(v1.w);
    }
    if (e < e1) {
        uint4 v0 = gp[(size_t)col[e] * 16];
        acc[0] += blo(v0.x); acc[1] += bhi(v0.x);
        acc[2] += blo(v0.y); acc[3] += bhi(v0.y);
        acc[4] += blo(v0.z); acc[5] += bhi(v0.z);
        acc[6] += blo(v0.w); acc[7] += bhi(v0.w);
    }

    float di = dinv[i];
    const float4* b4 = (const float4*)(bias + half * 64);
    float4 bv0 = b4[c * 2], bv1 = b4[c * 2 + 1];
    float r0[8];
    r0[0] = fmaf(acc[0], di, bv0.x);
    r0[1] = fmaf(acc[1], di, bv0.y);
    r0[2] = fmaf(acc[2], di, bv0.z);
    r0[3] = fmaf(acc[3], di, bv0.w);
    r0[4] = fmaf(acc[4], di, bv1.x);
    r0[5] = fmaf(acc[5], di, bv1.y);
    r0[6] = fmaf(acc[6], di, bv1.z);
    r0[7] = fmaf(acc[7], di, bv1.w);
    float* o = outv + (size_t)i * 128 + half * 64 + c * 8;
    f32x4 a = *(f32x4*)&r0[0];
    f32x4 b = *(f32x4*)&r0[4];
    __builtin_nontemporal_store(a, (f32x4*)o);
    __builtin_nontemporal_store(b, (f32x4*)(o + 4));
}

extern "C" void kernel_launch(void* const* d_in, const int* in_sizes, int n_in,
                              void* d_out, int out_size, void* d_ws, size_t ws_size,
                              hipStream_t stream) {
    const float* x      = (const float*)d_in[0];
    const int*   ei     = (const int*)d_in[1];
    const float* gate_W = (const float*)d_in[2];
    const float* gate_b = (const float*)d_in[3];
    const float* W1     = (const float*)d_in[4];
    const float* b1     = (const float*)d_in[5];
    const float* W2     = (const float*)d_in[6];
    const float* b2     = (const float*)d_in[7];
    float* out = (float*)d_out;

    const int N = in_sizes[0] / 128;
    const int E = in_sizes[1] / 2;
    const int* src = ei;
    const int* dst = ei + E;
    const int NB = (N + BUCKET_W - 1) / BUCKET_W;

    char* p = (char*)d_ws;
    auto alloc = [&](size_t bytes) { char* q = p; p += (bytes + 255) & ~(size_t)255; return q; };
    int*   rowptr  = (int*)alloc(((size_t)N + 1) * 4);
    float* dinv    = (float*)alloc((size_t)N * 4);
    int*   colb    = (int*)alloc((size_t)E * 4);
    int*   bcursor = (int*)alloc((size_t)NB * 4);
    int*   bbase   = (int*)alloc(((size_t)NB + 1) * 4);
    uint4* wimg    = (uint4*)alloc((size_t)3 * 2048 * 16);
    unsigned int*   part   = (unsigned int*)alloc((size_t)NB * CAP * 4);
    unsigned short* hpack  = (unsigned short*)alloc((size_t)N * 128 * 2);
    unsigned short* g16    = (unsigned short*)alloc((size_t)N * 128 * 2);
    unsigned short* g2buf  = (unsigned short*)alloc((size_t)N * 128 * 2);

    const int pblocks = 256;
    const int chunk = (E + pblocks - 1) / pblocks;
    int gblocks = (N + 127) / 128;
    int fblocks = (N + 31) / 32;
    int nhb = (N + 31) / 32;

    prepinit_kernel<<<13, 512, 0, stream>>>(gate_W, W1, W2, wimg, bcursor, NB);
    pg_kernel<<<256 + gblocks, 512, 0, stream>>>(src, dst, bcursor, part, E, NB, chunk,
                                                 x, wimg, gate_b, hpack, N);
    bucket_scan_kernel<<<1, 512, 0, stream>>>(bcursor, bbase, NB);
    fg_kernel<<<NB + gblocks, 512, 0, stream>>>(part, bbase, rowptr, dinv, colb, N, NB,
                                                hpack, wimg + 2048, g16);
    spmm_gemm_kernel<<<fblocks, 256, 0, stream>>>((const uint4*)g16, rowptr, colb,
                                                  dinv, b1, wimg + 4096, g2buf, N);
    spmm_kernel<<<2 * nhb, 256, 0, stream>>>((const uint4*)g2buf, rowptr, colb,
                                             dinv, b2, out, N, nhb);
}